// Round 12
// baseline (111.038 us; speedup 1.0000x reference)
//
#include <hip/hip_runtime.h>
#include <math.h>

// Problem constants
#define NQ     25      // number of query images (= n_support)
#define NWAY   5
#define KSHOT  5
#define CC     640     // channels (k-dim of S gemm; 640 = 20*32)
#define HW     196     // 14*14
#define NSL    980     // NWAY*HW support locations
#define NSLP   992     // padded K for M-gemm (31*32)
#define RPQ    208     // padded row count per query (13*16)
#define BROWS  1024    // snbt allocated rows (8 n-tiles of 128)
#define MST    200     // M row stride in bf16 (400B, 16B-aligned; 25 bf16x8 chunks)
#define MRA    208     // M allocated rows per query
#define GAMMA  20.0f
#define GAMMA2 10.0f
#define NITER  8       // ||M||_1 = 0.25 -> tail 0.25^9/0.75 ~ 5e-6 vs threshold 1.77e-2

typedef __bf16 bf16;
typedef _Float16 f16;
typedef __attribute__((ext_vector_type(8))) __bf16 bf16x8;
typedef __attribute__((ext_vector_type(4))) float f32x4;

// ---------------------------------------------------------------------------
// K1: prototype mean + per-location L2 normalization -> TRANSPOSED bf16.
// qnbt[q][m][c] (rows padded to RPQ), snbt[j][c] (rows padded to BROWS).
// ---------------------------------------------------------------------------
__global__ __launch_bounds__(256) void k_norm(const float* __restrict__ feat,
                                              bf16* __restrict__ qnbt,
                                              bf16* __restrict__ snbt) {
    const int by = blockIdx.y;
    const int lx = threadIdx.x & 15;
    const int cg = threadIdx.x >> 4;
    const int l  = blockIdx.x * 16 + lx;
    const bool act = (l < HW);
    const int c0 = cg * 40;
    __shared__ float pr[16][17];

    float xv[40];
    float ss = 0.f;
    if (by < NQ) {
        const float* f = feat + (size_t)(NQ + by) * CC * HW;
#pragma unroll
        for (int i = 0; i < 40; ++i) {
            float x = act ? f[(c0 + i) * HW + l] : 0.f;
            xv[i] = x; ss += x * x;
        }
    } else {
        const int s = by - NQ;
        const float* f = feat + (size_t)(NQ + s * KSHOT) * CC * HW;
        const size_t img = (size_t)CC * HW;
#pragma unroll
        for (int i = 0; i < 40; ++i) {
            float m = 0.f;
            if (act) {
                const float* p = f + (c0 + i) * HW + l;
                m = 0.2f * (p[0] + p[img] + p[2 * img] + p[3 * img] + p[4 * img]);
            }
            xv[i] = m; ss += m * m;
        }
    }
    pr[cg][lx] = ss;
    __syncthreads();
    if (cg == 0) {
        float a = 0.f;
#pragma unroll
        for (int k = 0; k < 16; ++k) a += pr[k][lx];
        pr[0][lx] = 1.f / (1e-16f + sqrtf(a));
    }
    __syncthreads();
    const float inv = pr[0][lx];
    if (act) {
        bf16* o = (by < NQ) ? (qnbt + ((size_t)by * RPQ + l) * CC)
                            : (snbt + ((size_t)(by - NQ) * HW + l) * CC);
#pragma unroll
        for (int i = 0; i < 40; ++i) o[c0 + i] = (bf16)(xv[i] * inv);
    }
}

// ---------------------------------------------------------------------------
// K2: S[q][m][j] = sum_c qnbt[q][m][c] * snbt[j][c]  -- LDS-tiled MFMA GEMM.
// 128x128 tile, BK=64 (10 k-steps, 2 MFMA sub-steps each), 256 threads =
// 4 waves (2x2), each wave 64x64 (4x4 of 16x16).  m-tiles rows {0, 80}
// (overlap written twice, identical values). grid (8 n, 2 m, 25 q).
// S stored as fp16 (fp32 accum, one rounding on store).
// ---------------------------------------------------------------------------
#define ASTR2 72   // LDS row stride in bf16 (144B): 2-way bank alias only
__global__ __launch_bounds__(256) void k_sgemm(const bf16* __restrict__ qnbt,
                                               const bf16* __restrict__ snbt,
                                               f16* __restrict__ S) {
    const int q  = blockIdx.z;
    const int m0 = blockIdx.y * 80;          // {0, 80}
    const int n0 = blockIdx.x * 128;         // 0..896
    __shared__ bf16 As[128 * ASTR2];
    __shared__ bf16 Bs[128 * ASTR2];
    const int t = threadIdx.x;
    const int lane = t & 63, w = t >> 6;
    const int wr = w >> 1, wc = w & 1;
    const int lo = lane & 15, hi = lane >> 4;
    const int sr = t >> 1, sh = (t & 1) * 32;   // stage: row, col-half (bf16)

    const bf16* Aq = qnbt + (size_t)q * RPQ * CC;
    f32x4 acc[4][4] = {};

    for (int k0 = 0; k0 < CC; k0 += 64) {
        bf16x8 a0 = *reinterpret_cast<const bf16x8*>(&Aq[(size_t)(m0 + sr) * CC + k0 + sh]);
        bf16x8 a1 = *reinterpret_cast<const bf16x8*>(&Aq[(size_t)(m0 + sr) * CC + k0 + sh + 8]);
        bf16x8 a2 = *reinterpret_cast<const bf16x8*>(&Aq[(size_t)(m0 + sr) * CC + k0 + sh + 16]);
        bf16x8 a3 = *reinterpret_cast<const bf16x8*>(&Aq[(size_t)(m0 + sr) * CC + k0 + sh + 24]);
        bf16x8 b0 = *reinterpret_cast<const bf16x8*>(&snbt[(size_t)(n0 + sr) * CC + k0 + sh]);
        bf16x8 b1 = *reinterpret_cast<const bf16x8*>(&snbt[(size_t)(n0 + sr) * CC + k0 + sh + 8]);
        bf16x8 b2 = *reinterpret_cast<const bf16x8*>(&snbt[(size_t)(n0 + sr) * CC + k0 + sh + 16]);
        bf16x8 b3 = *reinterpret_cast<const bf16x8*>(&snbt[(size_t)(n0 + sr) * CC + k0 + sh + 24]);
        __syncthreads();   // previous step's fragment reads done
        *reinterpret_cast<bf16x8*>(&As[sr * ASTR2 + sh])      = a0;
        *reinterpret_cast<bf16x8*>(&As[sr * ASTR2 + sh + 8])  = a1;
        *reinterpret_cast<bf16x8*>(&As[sr * ASTR2 + sh + 16]) = a2;
        *reinterpret_cast<bf16x8*>(&As[sr * ASTR2 + sh + 24]) = a3;
        *reinterpret_cast<bf16x8*>(&Bs[sr * ASTR2 + sh])      = b0;
        *reinterpret_cast<bf16x8*>(&Bs[sr * ASTR2 + sh + 8])  = b1;
        *reinterpret_cast<bf16x8*>(&Bs[sr * ASTR2 + sh + 16]) = b2;
        *reinterpret_cast<bf16x8*>(&Bs[sr * ASTR2 + sh + 24]) = b3;
        __syncthreads();
#pragma unroll
        for (int kk = 0; kk < 2; ++kk) {
            bf16x8 af[4], bf[4];
#pragma unroll
            for (int mi = 0; mi < 4; ++mi)
                af[mi] = *reinterpret_cast<const bf16x8*>(
                    &As[(wr * 64 + mi * 16 + lo) * ASTR2 + kk * 32 + hi * 8]);
#pragma unroll
            for (int ni = 0; ni < 4; ++ni)
                bf[ni] = *reinterpret_cast<const bf16x8*>(
                    &Bs[(wc * 64 + ni * 16 + lo) * ASTR2 + kk * 32 + hi * 8]);
#pragma unroll
            for (int mi = 0; mi < 4; ++mi)
#pragma unroll
                for (int ni = 0; ni < 4; ++ni)
                    acc[mi][ni] = __builtin_amdgcn_mfma_f32_16x16x32_bf16(af[mi], bf[ni], acc[mi][ni], 0, 0, 0);
        }
    }

    f16* Sq = S + (size_t)q * HW * NSL;
#pragma unroll
    for (int mi = 0; mi < 4; ++mi) {
#pragma unroll
        for (int ni = 0; ni < 4; ++ni) {
            const int j = n0 + wc * 64 + ni * 16 + lo;
            if (j >= NSL) continue;
#pragma unroll
            for (int r = 0; r < 4; ++r) {
                const int m = m0 + wr * 64 + mi * 16 + hi * 4 + r;
                if (m < HW) Sq[(size_t)m * NSL + j] = (f16)acc[mi][ni][r];
            }
        }
    }
}

// ---------------------------------------------------------------------------
// K3: fused softmaxes (S is fp16).
//   Blocks [0, 1225): Ts row softmax, WAVE-PER-ROW (4 rows/block, no
//     barriers) + fused class row-sums R.
//   Blocks [1225, 1225+NQ*16): Tq column softmax.
// ---------------------------------------------------------------------------
#define TSBLK (NQ * HW / 4)   // 1225
__global__ __launch_bounds__(256) void k_soft(const f16* __restrict__ S,
                                              bf16* __restrict__ Ts,
                                              bf16* __restrict__ Tq,
                                              float* __restrict__ R) {
    const int bid = blockIdx.x;
    if (bid < TSBLK) {
        // ---- Ts role: one WAVE per (q,m) row; no __syncthreads ----
        const int lane = threadIdx.x & 63, w = threadIdx.x >> 6;
        const int qm = bid * 4 + w;          // < 4900
        const int q = qm / HW, m = qm - q * HW;
        const f16* row = S + (size_t)qm * NSL;
        bf16* orow = Ts + ((size_t)q * RPQ + m) * NSLP;
        float x[16];
        float mx = -1e30f;
#pragma unroll
        for (int p = 0; p < 16; ++p) {
            int j = lane + p * 64;
            x[p] = (j < NSL) ? (float)row[j] : -1e30f;
            mx = fmaxf(mx, x[p]);
        }
        for (int d = 32; d; d >>= 1) mx = fmaxf(mx, __shfl_xor(mx, d));
        float sum = 0.f;
#pragma unroll
        for (int p = 0; p < 16; ++p) {
            x[p] = expf(GAMMA * (x[p] - mx));   // pads -> exp(-inf) = 0
            sum += x[p];
        }
        for (int d = 32; d; d >>= 1) sum += __shfl_xor(sum, d);
        const float inv = 1.f / sum;
        float racc[NWAY];
#pragma unroll
        for (int s = 0; s < NWAY; ++s) racc[s] = 0.f;
#pragma unroll
        for (int p = 0; p < 16; ++p) {
            int j = lane + p * 64;
            if (j < NSL) {
                float val = x[p] * inv;
                orow[j] = (bf16)val;
                int cls = j / HW;
#pragma unroll
                for (int s = 0; s < NWAY; ++s) racc[s] += (cls == s) ? val : 0.f;
            } else if (j < NSLP) {
                orow[j] = (bf16)0.f;   // zero K-pad
            }
        }
#pragma unroll
        for (int s = 0; s < NWAY; ++s)
            for (int d = 32; d; d >>= 1) racc[s] += __shfl_xor(racc[s], d);
        if (lane == 0) {
#pragma unroll
            for (int s = 0; s < NWAY; ++s)
                R[((size_t)q * NWAY + s) * HW + m] = racc[s];
        }
    } else {
        // ---- Tq role: 64 columns per block, 4 m-groups of 49 ----
        const int idx2 = bid - TSBLK;
        const int q  = idx2 >> 4;
        const int bx = idx2 & 15;
        const int tx = threadIdx.x & 63;
        const int tg = threadIdx.x >> 6;
        const int j  = bx * 64 + tx;
        const int m0 = tg * 49;
        const f16* base = S + (size_t)q * HW * NSL;
        bf16* ob = Tq + (size_t)q * RPQ * NSLP;
        __shared__ float rmax[4][64], rsum[4][64];
        float xv[49];
        float mx = -1e30f;
        if (j < NSL) {
#pragma unroll
            for (int i = 0; i < 49; ++i) {
                xv[i] = (float)base[(m0 + i) * NSL + j];
                mx = fmaxf(mx, xv[i]);
            }
        }
        rmax[tg][tx] = mx;
        __syncthreads();
        mx = fmaxf(fmaxf(rmax[0][tx], rmax[1][tx]), fmaxf(rmax[2][tx], rmax[3][tx]));
        float sum = 0.f;
        if (j < NSL) {
#pragma unroll
            for (int i = 0; i < 49; ++i) {
                xv[i] = expf(GAMMA2 * (xv[i] - mx));
                sum += xv[i];
            }
        }
        rsum[tg][tx] = sum;
        __syncthreads();
        const float inv = 1.f / (rsum[0][tx] + rsum[1][tx] + rsum[2][tx] + rsum[3][tx]);
        if (j < NSL) {
#pragma unroll
            for (int i = 0; i < 49; ++i) ob[(size_t)(m0 + i) * NSLP + j] = (bf16)(xv[i] * inv);
        } else if (j < NSLP) {
#pragma unroll
            for (int i = 0; i < 49; ++i) ob[(size_t)(m0 + i) * NSLP + j] = (bf16)0.f;
        }
    }
}

// ---------------------------------------------------------------------------
// K4: M = 0.25 * Tq (196x992) * Ts^T (992x196) -> bf16, row stride MST=200.
// LDS-tiled 128x128 (proven k_sgemm structure), BK=32, 256 threads = 4 waves.
// Tile offsets {0, 68} both axes: all reads stay in valid rows 0..195
// (no garbage), overlap region computed twice with identical values.
// grid (2 j, 2 i, 25 q) = 100 blocks.  jt==0 blocks also emit
// rhs[q][i] = 1 + 0.5*rowsum(Tq[i][:]) from the staged A values.
// ---------------------------------------------------------------------------
#define MSTR 40   // LDS row stride in bf16 (80B)
__global__ __launch_bounds__(256) void k_mgemm(const bf16* __restrict__ Tq,
                                               const bf16* __restrict__ Ts,
                                               bf16* __restrict__ Mb,
                                               float* __restrict__ rhs) {
    const int q  = blockIdx.z;
    const int m0 = blockIdx.y * 68;          // {0, 68}
    const int n0 = blockIdx.x * 68;          // {0, 68}
    __shared__ bf16 As[128 * MSTR];
    __shared__ bf16 Bs[128 * MSTR];
    const int t = threadIdx.x;
    const int lane = t & 63, w = t >> 6;
    const int wr = w >> 1, wc = w & 1;
    const int lo = lane & 15, hi = lane >> 4;
    const int sr = t >> 1, sh = (t & 1) * 16;   // stage: row, 16-col half
    const bool dorhs = (blockIdx.x == 0);

    const bf16* Aq = Tq + (size_t)q * RPQ * NSLP;
    const bf16* Bq = Ts + (size_t)q * RPQ * NSLP;
    f32x4 acc[4][4] = {};
    float rsum = 0.f;

    for (int k0 = 0; k0 < NSLP; k0 += 32) {
        bf16x8 a0 = *reinterpret_cast<const bf16x8*>(&Aq[(size_t)(m0 + sr) * NSLP + k0 + sh]);
        bf16x8 a1 = *reinterpret_cast<const bf16x8*>(&Aq[(size_t)(m0 + sr) * NSLP + k0 + sh + 8]);
        bf16x8 b0 = *reinterpret_cast<const bf16x8*>(&Bq[(size_t)(n0 + sr) * NSLP + k0 + sh]);
        bf16x8 b1 = *reinterpret_cast<const bf16x8*>(&Bq[(size_t)(n0 + sr) * NSLP + k0 + sh + 8]);
        if (dorhs) {
#pragma unroll
            for (int e = 0; e < 8; ++e) rsum += (float)a0[e] + (float)a1[e];
        }
        __syncthreads();   // previous step's fragment reads done
        *reinterpret_cast<bf16x8*>(&As[sr * MSTR + sh])     = a0;
        *reinterpret_cast<bf16x8*>(&As[sr * MSTR + sh + 8]) = a1;
        *reinterpret_cast<bf16x8*>(&Bs[sr * MSTR + sh])     = b0;
        *reinterpret_cast<bf16x8*>(&Bs[sr * MSTR + sh + 8]) = b1;
        __syncthreads();
        bf16x8 af[4], bfr[4];
#pragma unroll
        for (int mi = 0; mi < 4; ++mi)
            af[mi] = *reinterpret_cast<const bf16x8*>(&As[(wr * 64 + mi * 16 + lo) * MSTR + hi * 8]);
#pragma unroll
        for (int ni = 0; ni < 4; ++ni)
            bfr[ni] = *reinterpret_cast<const bf16x8*>(&Bs[(wc * 64 + ni * 16 + lo) * MSTR + hi * 8]);
#pragma unroll
        for (int mi = 0; mi < 4; ++mi)
#pragma unroll
            for (int ni = 0; ni < 4; ++ni)
                acc[mi][ni] = __builtin_amdgcn_mfma_f32_16x16x32_bf16(af[mi], bfr[ni], acc[mi][ni], 0, 0, 0);
    }

    if (dorhs) {
        rsum += __shfl_xor(rsum, 1);        // combine the two col-halves of row sr
        const int i = m0 + sr;
        if ((t & 1) == 0 && i < HW) rhs[q * HW + i] = 1.f + 0.5f * rsum;
    }

    bf16* Mq = Mb + (size_t)q * MRA * MST;
#pragma unroll
    for (int mi = 0; mi < 4; ++mi) {
#pragma unroll
        for (int ni = 0; ni < 4; ++ni) {
            const int j = n0 + wc * 64 + ni * 16 + lo;     // <= 195
#pragma unroll
            for (int r = 0; r < 4; ++r) {
                const int i = m0 + wr * 64 + mi * 16 + hi * 4 + r;   // <= 195
                Mq[(size_t)i * MST + j] = (bf16)(0.25f * acc[mi][ni][r]);
            }
        }
    }
}

// ---------------------------------------------------------------------------
// K5: per-query Katz solve, 1024 threads (16 waves).  Minimal work:
//   - M (bf16, 78.4 KB) -> LDS; rhs read from global (precomputed by k_mgemm)
//   - NITER x (v <- rhs + M v): 4 col-quarters/row, LDS partial reduce
//   - out[q][s] = (R[s].v) / total
// Ms cols 196..199 hold stale data but are multiplied by zero v-pads.
// ---------------------------------------------------------------------------
__global__ __launch_bounds__(1024) void k_solve2(const bf16* __restrict__ Mb,
                                                 const float* __restrict__ rhs,
                                                 const float* __restrict__ R,
                                                 float* __restrict__ out) {
    const int q = blockIdx.x;
    __shared__ __align__(16) bf16 Ms[HW * MST];            // 78,400 B
    __shared__ __align__(16) float va[MST], vb[MST];
    __shared__ float part[4][256];
    __shared__ float rhsl[HW];
    __shared__ float cls[NWAY];
    const int t = threadIdx.x, lane = t & 63, w = t >> 6;

    // --- M -> LDS (identical layout, contiguous bf16x8 copy) ---
    const bf16x8* gm = reinterpret_cast<const bf16x8*>(Mb + (size_t)q * MRA * MST);
    bf16x8* lm = reinterpret_cast<bf16x8*>(Ms);
    for (int i = t; i < HW * (MST / 8); i += 1024) lm[i] = gm[i];

    // --- rhs from global ---
    if (t < MST) {
        float r = (t < HW) ? rhs[q * HW + t] : 0.f;
        if (t < HW) rhsl[t] = r;
        va[t] = r; vb[t] = 0.f;
    }
    __syncthreads();

    // --- iterations ---
    const int r = t & 255, qd = t >> 8;
    const int cstart = (qd == 0) ? 0 : 7 + 6 * (qd - 1);   // {0,7,13,19}
    const int ccnt   = (qd == 0) ? 7 : 6;                  // 25 chunks = 200 cols
    for (int it = 0; it < NITER; ++it) {
        const float* src = (it & 1) ? vb : va;
        float* dst = (it & 1) ? va : vb;
        float a = 0.f;
        if (r < HW) {
            const bf16x8* mrow = reinterpret_cast<const bf16x8*>(&Ms[r * MST]);
            for (int c = cstart; c < cstart + ccnt; ++c) {
                bf16x8 mv = mrow[c];
                const float* sp = &src[c * 8];
#pragma unroll
                for (int e = 0; e < 8; ++e) a += (float)mv[e] * sp[e];
            }
        }
        part[qd][r] = a;
        __syncthreads();
        if (qd == 0 && r < HW)
            dst[r] = rhsl[r] + (part[0][r] + part[1][r] + part[2][r] + part[3][r]);
        __syncthreads();
    }
    // NITER even -> final v in va

    if (w < NWAY) {
        const float* Rs = R + ((size_t)q * NWAY + w) * HW;
        float a = 0.f;
        for (int m = lane; m < HW; m += 64) a += va[m] * Rs[m];
        for (int d = 32; d; d >>= 1) a += __shfl_xor(a, d);
        if (lane == 0) cls[w] = a;
    }
    __syncthreads();
    if (t == 0) {
        float tot = cls[0] + cls[1] + cls[2] + cls[3] + cls[4];
        float invt = 1.f / tot;
        for (int s = 0; s < NWAY; ++s) out[q * NWAY + s] = cls[s] * invt;
    }
}

// ---------------------------------------------------------------------------
extern "C" void kernel_launch(void* const* d_in, const int* in_sizes, int n_in,
                              void* d_out, int out_size, void* d_ws, size_t ws_size,
                              hipStream_t stream) {
    const float* feat = (const float*)d_in[0];
    float* out = (float*)d_out;
    char* w = (char*)d_ws;

    // workspace layout (16B-aligned)
    f16*   S    = (f16*)w;    w += sizeof(f16)   * (size_t)NQ * HW * NSL;   //  9.61 MB
    bf16*  Ts   = (bf16*)w;   w += sizeof(bf16)  * (size_t)NQ * RPQ * NSLP; // 10.32 MB
    bf16*  Tq   = (bf16*)w;   w += sizeof(bf16)  * (size_t)NQ * RPQ * NSLP; // 10.32 MB
    bf16*  qnbt = (bf16*)w;   w += sizeof(bf16)  * (size_t)NQ * RPQ * CC;   //  6.66 MB
    bf16*  snbt = (bf16*)w;   w += sizeof(bf16)  * (size_t)BROWS * CC;      //  1.31 MB
    float* R    = (float*)w;  w += sizeof(float) * (size_t)NQ * NWAY * HW;
    float* rhs  = (float*)w;  w += sizeof(float) * (size_t)NQ * HW;
    // S is dead after both softmaxes -> bf16 M aliases it (2.08 MB <= 9.6 MB)
    bf16* Mb = (bf16*)S;

    k_norm  <<<dim3(13, NQ + NWAY), 256, 0, stream>>>(feat, qnbt, snbt);
    k_sgemm <<<dim3(8, 2, NQ), 256, 0, stream>>>(qnbt, snbt, S);
    k_soft  <<<TSBLK + NQ * 16, 256, 0, stream>>>(S, Ts, Tq, R);
    k_mgemm <<<dim3(2, 2, NQ), 256, 0, stream>>>(Tq, Ts, Mb, rhs);
    k_solve2<<<NQ, 1024, 0, stream>>>(Mb, rhs, R, out);
}

// Round 13
// 100.443 us; speedup vs baseline: 1.1055x; 1.1055x over previous
//
#include <hip/hip_runtime.h>
#include <math.h>

// Problem constants
#define NQ     25      // number of query images (= n_support)
#define NWAY   5
#define KSHOT  5
#define CC     640     // channels (k-dim of S gemm; 640 = 20*32)
#define HW     196     // 14*14
#define NSL    980     // NWAY*HW support locations
#define NSLP   992     // padded K for M-gemm (31*32)
#define RPQ    208     // padded row count per query (13*16)
#define BROWS  1024    // snbt allocated rows (8 n-tiles of 128)
#define MST    200     // M row stride in bf16 (400B, 16B-aligned; 25 bf16x8 chunks)
#define MRA    208     // M allocated rows per query
#define GAMMA  20.0f
#define GAMMA2 10.0f
#define NITER  8       // ||M||_1 = 0.25 -> tail 0.25^9/0.75 ~ 5e-6 vs threshold 1.77e-2

typedef __bf16 bf16;
typedef _Float16 f16;
typedef __attribute__((ext_vector_type(8))) __bf16 bf16x8;
typedef __attribute__((ext_vector_type(4))) float f32x4;

// ---------------------------------------------------------------------------
// K1: prototype mean + per-location L2 normalization -> TRANSPOSED bf16.
// qnbt[q][m][c] (rows padded to RPQ), snbt[j][c] (rows padded to BROWS).
// ---------------------------------------------------------------------------
__global__ __launch_bounds__(256) void k_norm(const float* __restrict__ feat,
                                              bf16* __restrict__ qnbt,
                                              bf16* __restrict__ snbt) {
    const int by = blockIdx.y;
    const int lx = threadIdx.x & 15;
    const int cg = threadIdx.x >> 4;
    const int l  = blockIdx.x * 16 + lx;
    const bool act = (l < HW);
    const int c0 = cg * 40;
    __shared__ float pr[16][17];

    float xv[40];
    float ss = 0.f;
    if (by < NQ) {
        const float* f = feat + (size_t)(NQ + by) * CC * HW;
#pragma unroll
        for (int i = 0; i < 40; ++i) {
            float x = act ? f[(c0 + i) * HW + l] : 0.f;
            xv[i] = x; ss += x * x;
        }
    } else {
        const int s = by - NQ;
        const float* f = feat + (size_t)(NQ + s * KSHOT) * CC * HW;
        const size_t img = (size_t)CC * HW;
#pragma unroll
        for (int i = 0; i < 40; ++i) {
            float m = 0.f;
            if (act) {
                const float* p = f + (c0 + i) * HW + l;
                m = 0.2f * (p[0] + p[img] + p[2 * img] + p[3 * img] + p[4 * img]);
            }
            xv[i] = m; ss += m * m;
        }
    }
    pr[cg][lx] = ss;
    __syncthreads();
    if (cg == 0) {
        float a = 0.f;
#pragma unroll
        for (int k = 0; k < 16; ++k) a += pr[k][lx];
        pr[0][lx] = 1.f / (1e-16f + sqrtf(a));
    }
    __syncthreads();
    const float inv = pr[0][lx];
    if (act) {
        bf16* o = (by < NQ) ? (qnbt + ((size_t)by * RPQ + l) * CC)
                            : (snbt + ((size_t)(by - NQ) * HW + l) * CC);
#pragma unroll
        for (int i = 0; i < 40; ++i) o[c0 + i] = (bf16)(xv[i] * inv);
    }
}

// ---------------------------------------------------------------------------
// K2: S[q][m][j] = sum_c qnbt[q][m][c] * snbt[j][c]  -- LDS-tiled MFMA GEMM.
// 128x128 tile, BK=64 (10 k-steps, 2 MFMA sub-steps each), 256 threads =
// 4 waves (2x2), each wave 64x64 (4x4 of 16x16).  m-tiles rows {0, 80}
// (overlap written twice, identical values). grid (8 n, 2 m, 25 q).
// S stored as fp16 (fp32 accum, one rounding on store).
// ---------------------------------------------------------------------------
#define ASTR2 72   // LDS row stride in bf16 (144B): 2-way bank alias only
__global__ __launch_bounds__(256) void k_sgemm(const bf16* __restrict__ qnbt,
                                               const bf16* __restrict__ snbt,
                                               f16* __restrict__ S) {
    const int q  = blockIdx.z;
    const int m0 = blockIdx.y * 80;          // {0, 80}
    const int n0 = blockIdx.x * 128;         // 0..896
    __shared__ bf16 As[128 * ASTR2];
    __shared__ bf16 Bs[128 * ASTR2];
    const int t = threadIdx.x;
    const int lane = t & 63, w = t >> 6;
    const int wr = w >> 1, wc = w & 1;
    const int lo = lane & 15, hi = lane >> 4;
    const int sr = t >> 1, sh = (t & 1) * 32;   // stage: row, col-half (bf16)

    const bf16* Aq = qnbt + (size_t)q * RPQ * CC;
    f32x4 acc[4][4] = {};

    for (int k0 = 0; k0 < CC; k0 += 64) {
        bf16x8 a0 = *reinterpret_cast<const bf16x8*>(&Aq[(size_t)(m0 + sr) * CC + k0 + sh]);
        bf16x8 a1 = *reinterpret_cast<const bf16x8*>(&Aq[(size_t)(m0 + sr) * CC + k0 + sh + 8]);
        bf16x8 a2 = *reinterpret_cast<const bf16x8*>(&Aq[(size_t)(m0 + sr) * CC + k0 + sh + 16]);
        bf16x8 a3 = *reinterpret_cast<const bf16x8*>(&Aq[(size_t)(m0 + sr) * CC + k0 + sh + 24]);
        bf16x8 b0 = *reinterpret_cast<const bf16x8*>(&snbt[(size_t)(n0 + sr) * CC + k0 + sh]);
        bf16x8 b1 = *reinterpret_cast<const bf16x8*>(&snbt[(size_t)(n0 + sr) * CC + k0 + sh + 8]);
        bf16x8 b2 = *reinterpret_cast<const bf16x8*>(&snbt[(size_t)(n0 + sr) * CC + k0 + sh + 16]);
        bf16x8 b3 = *reinterpret_cast<const bf16x8*>(&snbt[(size_t)(n0 + sr) * CC + k0 + sh + 24]);
        __syncthreads();   // previous step's fragment reads done
        *reinterpret_cast<bf16x8*>(&As[sr * ASTR2 + sh])      = a0;
        *reinterpret_cast<bf16x8*>(&As[sr * ASTR2 + sh + 8])  = a1;
        *reinterpret_cast<bf16x8*>(&As[sr * ASTR2 + sh + 16]) = a2;
        *reinterpret_cast<bf16x8*>(&As[sr * ASTR2 + sh + 24]) = a3;
        *reinterpret_cast<bf16x8*>(&Bs[sr * ASTR2 + sh])      = b0;
        *reinterpret_cast<bf16x8*>(&Bs[sr * ASTR2 + sh + 8])  = b1;
        *reinterpret_cast<bf16x8*>(&Bs[sr * ASTR2 + sh + 16]) = b2;
        *reinterpret_cast<bf16x8*>(&Bs[sr * ASTR2 + sh + 24]) = b3;
        __syncthreads();
#pragma unroll
        for (int kk = 0; kk < 2; ++kk) {
            bf16x8 af[4], bf[4];
#pragma unroll
            for (int mi = 0; mi < 4; ++mi)
                af[mi] = *reinterpret_cast<const bf16x8*>(
                    &As[(wr * 64 + mi * 16 + lo) * ASTR2 + kk * 32 + hi * 8]);
#pragma unroll
            for (int ni = 0; ni < 4; ++ni)
                bf[ni] = *reinterpret_cast<const bf16x8*>(
                    &Bs[(wc * 64 + ni * 16 + lo) * ASTR2 + kk * 32 + hi * 8]);
#pragma unroll
            for (int mi = 0; mi < 4; ++mi)
#pragma unroll
                for (int ni = 0; ni < 4; ++ni)
                    acc[mi][ni] = __builtin_amdgcn_mfma_f32_16x16x32_bf16(af[mi], bf[ni], acc[mi][ni], 0, 0, 0);
        }
    }

    f16* Sq = S + (size_t)q * HW * NSL;
#pragma unroll
    for (int mi = 0; mi < 4; ++mi) {
#pragma unroll
        for (int ni = 0; ni < 4; ++ni) {
            const int j = n0 + wc * 64 + ni * 16 + lo;
            if (j >= NSL) continue;
#pragma unroll
            for (int r = 0; r < 4; ++r) {
                const int m = m0 + wr * 64 + mi * 16 + hi * 4 + r;
                if (m < HW) Sq[(size_t)m * NSL + j] = (f16)acc[mi][ni][r];
            }
        }
    }
}

// ---------------------------------------------------------------------------
// K3: fused softmaxes (S is fp16).
//   Blocks [0, 1225): Ts row softmax, WAVE-PER-ROW (4 rows/block, no
//     barriers) + fused class row-sums R.
//   Blocks [1225, 1225+NQ*16): Tq column softmax.
// ---------------------------------------------------------------------------
#define TSBLK (NQ * HW / 4)   // 1225
__global__ __launch_bounds__(256) void k_soft(const f16* __restrict__ S,
                                              bf16* __restrict__ Ts,
                                              bf16* __restrict__ Tq,
                                              float* __restrict__ R) {
    const int bid = blockIdx.x;
    if (bid < TSBLK) {
        // ---- Ts role: one WAVE per (q,m) row; no __syncthreads ----
        const int lane = threadIdx.x & 63, w = threadIdx.x >> 6;
        const int qm = bid * 4 + w;          // < 4900
        const int q = qm / HW, m = qm - q * HW;
        const f16* row = S + (size_t)qm * NSL;
        bf16* orow = Ts + ((size_t)q * RPQ + m) * NSLP;
        float x[16];
        float mx = -1e30f;
#pragma unroll
        for (int p = 0; p < 16; ++p) {
            int j = lane + p * 64;
            x[p] = (j < NSL) ? (float)row[j] : -1e30f;
            mx = fmaxf(mx, x[p]);
        }
        for (int d = 32; d; d >>= 1) mx = fmaxf(mx, __shfl_xor(mx, d));
        float sum = 0.f;
#pragma unroll
        for (int p = 0; p < 16; ++p) {
            x[p] = expf(GAMMA * (x[p] - mx));   // pads -> exp(-inf) = 0
            sum += x[p];
        }
        for (int d = 32; d; d >>= 1) sum += __shfl_xor(sum, d);
        const float inv = 1.f / sum;
        float racc[NWAY];
#pragma unroll
        for (int s = 0; s < NWAY; ++s) racc[s] = 0.f;
#pragma unroll
        for (int p = 0; p < 16; ++p) {
            int j = lane + p * 64;
            if (j < NSL) {
                float val = x[p] * inv;
                orow[j] = (bf16)val;
                int cls = j / HW;
#pragma unroll
                for (int s = 0; s < NWAY; ++s) racc[s] += (cls == s) ? val : 0.f;
            } else if (j < NSLP) {
                orow[j] = (bf16)0.f;   // zero K-pad
            }
        }
#pragma unroll
        for (int s = 0; s < NWAY; ++s)
            for (int d = 32; d; d >>= 1) racc[s] += __shfl_xor(racc[s], d);
        if (lane == 0) {
#pragma unroll
            for (int s = 0; s < NWAY; ++s)
                R[((size_t)q * NWAY + s) * HW + m] = racc[s];
        }
    } else {
        // ---- Tq role: 64 columns per block, 4 m-groups of 49 ----
        const int idx2 = bid - TSBLK;
        const int q  = idx2 >> 4;
        const int bx = idx2 & 15;
        const int tx = threadIdx.x & 63;
        const int tg = threadIdx.x >> 6;
        const int j  = bx * 64 + tx;
        const int m0 = tg * 49;
        const f16* base = S + (size_t)q * HW * NSL;
        bf16* ob = Tq + (size_t)q * RPQ * NSLP;
        __shared__ float rmax[4][64], rsum[4][64];
        float xv[49];
        float mx = -1e30f;
        if (j < NSL) {
#pragma unroll
            for (int i = 0; i < 49; ++i) {
                xv[i] = (float)base[(m0 + i) * NSL + j];
                mx = fmaxf(mx, xv[i]);
            }
        }
        rmax[tg][tx] = mx;
        __syncthreads();
        mx = fmaxf(fmaxf(rmax[0][tx], rmax[1][tx]), fmaxf(rmax[2][tx], rmax[3][tx]));
        float sum = 0.f;
        if (j < NSL) {
#pragma unroll
            for (int i = 0; i < 49; ++i) {
                xv[i] = expf(GAMMA2 * (xv[i] - mx));
                sum += xv[i];
            }
        }
        rsum[tg][tx] = sum;
        __syncthreads();
        const float inv = 1.f / (rsum[0][tx] + rsum[1][tx] + rsum[2][tx] + rsum[3][tx]);
        if (j < NSL) {
#pragma unroll
            for (int i = 0; i < 49; ++i) ob[(size_t)(m0 + i) * NSLP + j] = (bf16)(xv[i] * inv);
        } else if (j < NSLP) {
#pragma unroll
            for (int i = 0; i < 49; ++i) ob[(size_t)(m0 + i) * NSLP + j] = (bf16)0.f;
        }
    }
}

// ---------------------------------------------------------------------------
// K4: M = 0.25 * Tq (196x992) * Ts^T (992x196) -> bf16, row stride MST=200.
// grid (4 j, 4 i, 25 q), 64 threads, one wave per 64x64 tile (400 blocks --
// the measured-good wide form; LDS-tiled 100-block variant regressed r11).
// jt==0 blocks also compute rhs[q][i] = 1 + 0.5*rowsum(Tq[i][:]) for free.
// ---------------------------------------------------------------------------
__global__ __launch_bounds__(64) void k_mgemm(const bf16* __restrict__ Tq,
                                              const bf16* __restrict__ Ts,
                                              bf16* __restrict__ Mb,
                                              float* __restrict__ rhs) {
    const int q  = blockIdx.z;
    const int it = blockIdx.y;
    const int jt = blockIdx.x;
    const int l  = threadIdx.x;
    const int lo = l & 15, hi = l >> 4;
    const bool dorhs = (jt == 0);
    const bf16* Ap[4];
    const bf16* Bp[4];
#pragma unroll
    for (int mi = 0; mi < 4; ++mi)
        Ap[mi] = Tq + ((size_t)q * RPQ + it * 64 + mi * 16 + lo) * NSLP + hi * 8;
#pragma unroll
    for (int ni = 0; ni < 4; ++ni)
        Bp[ni] = Ts + ((size_t)q * RPQ + jt * 64 + ni * 16 + lo) * NSLP + hi * 8;

    f32x4 acc[4][4] = {};
    float rsum[4] = {0.f, 0.f, 0.f, 0.f};
#pragma unroll 2
    for (int k0 = 0; k0 < NSLP; k0 += 32) {
        bf16x8 a[4], b[4];
#pragma unroll
        for (int mi = 0; mi < 4; ++mi) a[mi] = *reinterpret_cast<const bf16x8*>(Ap[mi] + k0);
#pragma unroll
        for (int ni = 0; ni < 4; ++ni) b[ni] = *reinterpret_cast<const bf16x8*>(Bp[ni] + k0);
        if (dorhs) {
#pragma unroll
            for (int mi = 0; mi < 4; ++mi)
#pragma unroll
                for (int e = 0; e < 8; ++e) rsum[mi] += (float)a[mi][e];
        }
#pragma unroll
        for (int mi = 0; mi < 4; ++mi)
#pragma unroll
            for (int ni = 0; ni < 4; ++ni)
                acc[mi][ni] = __builtin_amdgcn_mfma_f32_16x16x32_bf16(a[mi], b[ni], acc[mi][ni], 0, 0, 0);
    }

    if (dorhs) {
#pragma unroll
        for (int mi = 0; mi < 4; ++mi) {
            float v = rsum[mi];
            v += __shfl_xor(v, 16);
            v += __shfl_xor(v, 32);   // summed over the 4 hi-slices
            const int i = it * 64 + mi * 16 + lo;
            if (hi == 0 && i < HW) rhs[q * HW + i] = 1.f + 0.5f * v;
        }
    }

    bf16* Mq = Mb + (size_t)q * MRA * MST;
#pragma unroll
    for (int mi = 0; mi < 4; ++mi) {
#pragma unroll
        for (int ni = 0; ni < 4; ++ni) {
            const int j = jt * 64 + ni * 16 + lo;
            if (j >= MST) continue;
#pragma unroll
            for (int r = 0; r < 4; ++r) {
                const int i = it * 64 + mi * 16 + hi * 4 + r;
                if (i >= MRA) continue;
                Mq[(size_t)i * MST + j] =
                    (i < HW && j < HW) ? (bf16)(0.25f * acc[mi][ni][r]) : (bf16)0.f;
            }
        }
    }
}

// ---------------------------------------------------------------------------
// K5: per-query Katz solve, 1024 threads (16 waves).  Minimal work:
//   - M (bf16, 78.4 KB) -> LDS; rhs read from global (precomputed by k_mgemm)
//   - NITER x (v <- rhs + M v): 4 col-quarters/row, LDS partial reduce
//   - out[q][s] = (R[s].v) / total
// ---------------------------------------------------------------------------
__global__ __launch_bounds__(1024) void k_solve2(const bf16* __restrict__ Mb,
                                                 const float* __restrict__ rhs,
                                                 const float* __restrict__ R,
                                                 float* __restrict__ out) {
    const int q = blockIdx.x;
    __shared__ __align__(16) bf16 Ms[HW * MST];            // 78,400 B
    __shared__ __align__(16) float va[MST], vb[MST];
    __shared__ float part[4][256];
    __shared__ float rhsl[HW];
    __shared__ float cls[NWAY];
    const int t = threadIdx.x, lane = t & 63, w = t >> 6;

    // --- M -> LDS (identical layout, contiguous bf16x8 copy) ---
    const bf16x8* gm = reinterpret_cast<const bf16x8*>(Mb + (size_t)q * MRA * MST);
    bf16x8* lm = reinterpret_cast<bf16x8*>(Ms);
    for (int i = t; i < HW * (MST / 8); i += 1024) lm[i] = gm[i];

    // --- rhs from global ---
    if (t < MST) {
        float r = (t < HW) ? rhs[q * HW + t] : 0.f;
        if (t < HW) rhsl[t] = r;
        va[t] = r; vb[t] = 0.f;
    }
    __syncthreads();

    // --- iterations ---
    const int r = t & 255, qd = t >> 8;
    const int cstart = (qd == 0) ? 0 : 7 + 6 * (qd - 1);   // {0,7,13,19}
    const int ccnt   = (qd == 0) ? 7 : 6;                  // 25 chunks = 200 cols
    for (int it = 0; it < NITER; ++it) {
        const float* src = (it & 1) ? vb : va;
        float* dst = (it & 1) ? va : vb;
        float a = 0.f;
        if (r < HW) {
            const bf16x8* mrow = reinterpret_cast<const bf16x8*>(&Ms[r * MST]);
            for (int c = cstart; c < cstart + ccnt; ++c) {
                bf16x8 mv = mrow[c];
                const float* sp = &src[c * 8];
#pragma unroll
                for (int e = 0; e < 8; ++e) a += (float)mv[e] * sp[e];
            }
        }
        part[qd][r] = a;
        __syncthreads();
        if (qd == 0 && r < HW)
            dst[r] = rhsl[r] + (part[0][r] + part[1][r] + part[2][r] + part[3][r]);
        __syncthreads();
    }
    // NITER even -> final v in va

    if (w < NWAY) {
        const float* Rs = R + ((size_t)q * NWAY + w) * HW;
        float a = 0.f;
        for (int m = lane; m < HW; m += 64) a += va[m] * Rs[m];
        for (int d = 32; d; d >>= 1) a += __shfl_xor(a, d);
        if (lane == 0) cls[w] = a;
    }
    __syncthreads();
    if (t == 0) {
        float tot = cls[0] + cls[1] + cls[2] + cls[3] + cls[4];
        float invt = 1.f / tot;
        for (int s = 0; s < NWAY; ++s) out[q * NWAY + s] = cls[s] * invt;
    }
}

// ---------------------------------------------------------------------------
extern "C" void kernel_launch(void* const* d_in, const int* in_sizes, int n_in,
                              void* d_out, int out_size, void* d_ws, size_t ws_size,
                              hipStream_t stream) {
    const float* feat = (const float*)d_in[0];
    float* out = (float*)d_out;
    char* w = (char*)d_ws;

    // workspace layout (16B-aligned)
    f16*   S    = (f16*)w;    w += sizeof(f16)   * (size_t)NQ * HW * NSL;   //  9.61 MB
    bf16*  Ts   = (bf16*)w;   w += sizeof(bf16)  * (size_t)NQ * RPQ * NSLP; // 10.32 MB
    bf16*  Tq   = (bf16*)w;   w += sizeof(bf16)  * (size_t)NQ * RPQ * NSLP; // 10.32 MB
    bf16*  qnbt = (bf16*)w;   w += sizeof(bf16)  * (size_t)NQ * RPQ * CC;   //  6.66 MB
    bf16*  snbt = (bf16*)w;   w += sizeof(bf16)  * (size_t)BROWS * CC;      //  1.31 MB
    float* R    = (float*)w;  w += sizeof(float) * (size_t)NQ * NWAY * HW;
    float* rhs  = (float*)w;  w += sizeof(float) * (size_t)NQ * HW;
    // S is dead after both softmaxes -> bf16 M aliases it (2.08 MB <= 9.6 MB)
    bf16* Mb = (bf16*)S;

    k_norm  <<<dim3(13, NQ + NWAY), 256, 0, stream>>>(feat, qnbt, snbt);
    k_sgemm <<<dim3(8, 2, NQ), 256, 0, stream>>>(qnbt, snbt, S);
    k_soft  <<<TSBLK + NQ * 16, 256, 0, stream>>>(S, Ts, Tq, R);
    k_mgemm <<<dim3(4, 4, NQ), 64, 0, stream>>>(Tq, Ts, Mb, rhs);
    k_solve2<<<NQ, 1024, 0, stream>>>(Mb, rhs, R, out);
}

// Round 14
// 90.671 us; speedup vs baseline: 1.2246x; 1.1078x over previous
//
#include <hip/hip_runtime.h>
#include <math.h>

// Problem constants
#define NQ     25      // number of query images (= n_support)
#define NWAY   5
#define KSHOT  5
#define CC     640     // channels (k-dim of S gemm; 640 = 20*32)
#define HW     196     // 14*14
#define NSL    980     // NWAY*HW support locations
#define NSLP   992     // padded K for M-gemm (31*32)
#define RPQ    208     // padded row count per query (13*16)
#define BROWS  1024    // snbt allocated rows (8 n-tiles of 128)
#define MST    200     // M row stride in bf16 (400B, 16B-aligned; 25 bf16x8 chunks)
#define MRA    208     // M allocated rows per query
#define GAMMA  20.0f
#define GAMMA2 10.0f
#define NITER  6       // ||M||_1 = 0.25 -> tail 0.25^7/0.75 ~ 8e-5 vs threshold 1.77e-2

typedef __bf16 bf16;
typedef _Float16 f16;
typedef __attribute__((ext_vector_type(8))) __bf16 bf16x8;
typedef __attribute__((ext_vector_type(4))) float f32x4;

// ---------------------------------------------------------------------------
// K1: prototype mean + per-location L2 normalization -> TRANSPOSED bf16.
// float4-vectorized over locations: thread = (location-quad qd, 10-ch group).
// All global reads are aligned float4 (HW=196 = 49 quads; (c*HW+l0) = 4k).
// Valid quads are always fully in-bounds (196/4 exact); bx=12,qd>=1 inactive.
// ---------------------------------------------------------------------------
__global__ __launch_bounds__(256) void k_norm(const float* __restrict__ feat,
                                              bf16* __restrict__ qnbt,
                                              bf16* __restrict__ snbt) {
    const int by = blockIdx.y;
    const int t  = threadIdx.x;
    const int qd = t & 3;                     // location quad within 16-loc tile
    const int cg = t >> 2;                    // 64 channel groups of 10
    const int l0 = blockIdx.x * 16 + qd * 4;  // first of this thread's 4 locations
    const bool act = (l0 < HW);
    const int c0 = cg * 10;
    const int w  = t >> 6, lane = t & 63;
    __shared__ float4 pr2[4][4];              // [wave][qd] partial sums

    float4 xv[10];
    float4 ss = {0.f, 0.f, 0.f, 0.f};
    if (by < NQ) {
        const float* f = feat + (size_t)(NQ + by) * CC * HW;
        if (act) {
#pragma unroll
            for (int i = 0; i < 10; ++i) {
                float4 v = *reinterpret_cast<const float4*>(&f[(c0 + i) * HW + l0]);
                xv[i] = v;
                ss.x += v.x * v.x; ss.y += v.y * v.y;
                ss.z += v.z * v.z; ss.w += v.w * v.w;
            }
        }
    } else {
        const int s = by - NQ;
        const float* f = feat + (size_t)(NQ + s * KSHOT) * CC * HW;
        const size_t img = (size_t)CC * HW;
        if (act) {
#pragma unroll
            for (int i = 0; i < 10; ++i) {
                const float* p = &f[(c0 + i) * HW + l0];
                float4 v0 = *reinterpret_cast<const float4*>(p);
                float4 v1 = *reinterpret_cast<const float4*>(p + img);
                float4 v2 = *reinterpret_cast<const float4*>(p + 2 * img);
                float4 v3 = *reinterpret_cast<const float4*>(p + 3 * img);
                float4 v4 = *reinterpret_cast<const float4*>(p + 4 * img);
                float4 m;
                m.x = 0.2f * (v0.x + v1.x + v2.x + v3.x + v4.x);
                m.y = 0.2f * (v0.y + v1.y + v2.y + v3.y + v4.y);
                m.z = 0.2f * (v0.z + v1.z + v2.z + v3.z + v4.z);
                m.w = 0.2f * (v0.w + v1.w + v2.w + v3.w + v4.w);
                xv[i] = m;
                ss.x += m.x * m.x; ss.y += m.y * m.y;
                ss.z += m.z * m.z; ss.w += m.w * m.w;
            }
        }
    }
    // reduce over the 16 cg's within each wave (lane bits 2..5)
#pragma unroll
    for (int d = 4; d <= 32; d <<= 1) {
        ss.x += __shfl_xor(ss.x, d);
        ss.y += __shfl_xor(ss.y, d);
        ss.z += __shfl_xor(ss.z, d);
        ss.w += __shfl_xor(ss.w, d);
    }
    if (lane < 4) pr2[w][lane] = ss;          // lane == qd for lanes 0..3
    __syncthreads();
    const float4 s0 = pr2[0][qd], s1 = pr2[1][qd], s2 = pr2[2][qd], s3 = pr2[3][qd];
    float4 inv;
    inv.x = 1.f / (1e-16f + sqrtf(s0.x + s1.x + s2.x + s3.x));
    inv.y = 1.f / (1e-16f + sqrtf(s0.y + s1.y + s2.y + s3.y));
    inv.z = 1.f / (1e-16f + sqrtf(s0.z + s1.z + s2.z + s3.z));
    inv.w = 1.f / (1e-16f + sqrtf(s0.w + s1.w + s2.w + s3.w));
    if (act) {
        bf16* base = (by < NQ) ? (qnbt + ((size_t)by * RPQ + l0) * CC)
                               : (snbt + ((size_t)(by - NQ) * HW + l0) * CC);
#pragma unroll
        for (int i = 0; i < 10; ++i) {
            base[(size_t)0 * CC + c0 + i] = (bf16)(xv[i].x * inv.x);
            base[(size_t)1 * CC + c0 + i] = (bf16)(xv[i].y * inv.y);
            base[(size_t)2 * CC + c0 + i] = (bf16)(xv[i].z * inv.z);
            base[(size_t)3 * CC + c0 + i] = (bf16)(xv[i].w * inv.w);
        }
    }
}

// ---------------------------------------------------------------------------
// K2: S[q][m][j] = sum_c qnbt[q][m][c] * snbt[j][c]  -- LDS-tiled MFMA GEMM.
// 128x128 tile, BK=64 (10 k-steps, 2 MFMA sub-steps each), 256 threads =
// 4 waves (2x2), each wave 64x64 (4x4 of 16x16).  m-tiles rows {0, 80}
// (overlap written twice, identical values). grid (8 n, 2 m, 25 q).
// S stored as fp16 (fp32 accum, one rounding on store).
// ---------------------------------------------------------------------------
#define ASTR2 72   // LDS row stride in bf16 (144B): 2-way bank alias only
__global__ __launch_bounds__(256) void k_sgemm(const bf16* __restrict__ qnbt,
                                               const bf16* __restrict__ snbt,
                                               f16* __restrict__ S) {
    const int q  = blockIdx.z;
    const int m0 = blockIdx.y * 80;          // {0, 80}
    const int n0 = blockIdx.x * 128;         // 0..896
    __shared__ bf16 As[128 * ASTR2];
    __shared__ bf16 Bs[128 * ASTR2];
    const int t = threadIdx.x;
    const int lane = t & 63, w = t >> 6;
    const int wr = w >> 1, wc = w & 1;
    const int lo = lane & 15, hi = lane >> 4;
    const int sr = t >> 1, sh = (t & 1) * 32;   // stage: row, col-half (bf16)

    const bf16* Aq = qnbt + (size_t)q * RPQ * CC;
    f32x4 acc[4][4] = {};

    for (int k0 = 0; k0 < CC; k0 += 64) {
        bf16x8 a0 = *reinterpret_cast<const bf16x8*>(&Aq[(size_t)(m0 + sr) * CC + k0 + sh]);
        bf16x8 a1 = *reinterpret_cast<const bf16x8*>(&Aq[(size_t)(m0 + sr) * CC + k0 + sh + 8]);
        bf16x8 a2 = *reinterpret_cast<const bf16x8*>(&Aq[(size_t)(m0 + sr) * CC + k0 + sh + 16]);
        bf16x8 a3 = *reinterpret_cast<const bf16x8*>(&Aq[(size_t)(m0 + sr) * CC + k0 + sh + 24]);
        bf16x8 b0 = *reinterpret_cast<const bf16x8*>(&snbt[(size_t)(n0 + sr) * CC + k0 + sh]);
        bf16x8 b1 = *reinterpret_cast<const bf16x8*>(&snbt[(size_t)(n0 + sr) * CC + k0 + sh + 8]);
        bf16x8 b2 = *reinterpret_cast<const bf16x8*>(&snbt[(size_t)(n0 + sr) * CC + k0 + sh + 16]);
        bf16x8 b3 = *reinterpret_cast<const bf16x8*>(&snbt[(size_t)(n0 + sr) * CC + k0 + sh + 24]);
        __syncthreads();   // previous step's fragment reads done
        *reinterpret_cast<bf16x8*>(&As[sr * ASTR2 + sh])      = a0;
        *reinterpret_cast<bf16x8*>(&As[sr * ASTR2 + sh + 8])  = a1;
        *reinterpret_cast<bf16x8*>(&As[sr * ASTR2 + sh + 16]) = a2;
        *reinterpret_cast<bf16x8*>(&As[sr * ASTR2 + sh + 24]) = a3;
        *reinterpret_cast<bf16x8*>(&Bs[sr * ASTR2 + sh])      = b0;
        *reinterpret_cast<bf16x8*>(&Bs[sr * ASTR2 + sh + 8])  = b1;
        *reinterpret_cast<bf16x8*>(&Bs[sr * ASTR2 + sh + 16]) = b2;
        *reinterpret_cast<bf16x8*>(&Bs[sr * ASTR2 + sh + 24]) = b3;
        __syncthreads();
#pragma unroll
        for (int kk = 0; kk < 2; ++kk) {
            bf16x8 af[4], bf[4];
#pragma unroll
            for (int mi = 0; mi < 4; ++mi)
                af[mi] = *reinterpret_cast<const bf16x8*>(
                    &As[(wr * 64 + mi * 16 + lo) * ASTR2 + kk * 32 + hi * 8]);
#pragma unroll
            for (int ni = 0; ni < 4; ++ni)
                bf[ni] = *reinterpret_cast<const bf16x8*>(
                    &Bs[(wc * 64 + ni * 16 + lo) * ASTR2 + kk * 32 + hi * 8]);
#pragma unroll
            for (int mi = 0; mi < 4; ++mi)
#pragma unroll
                for (int ni = 0; ni < 4; ++ni)
                    acc[mi][ni] = __builtin_amdgcn_mfma_f32_16x16x32_bf16(af[mi], bf[ni], acc[mi][ni], 0, 0, 0);
        }
    }

    f16* Sq = S + (size_t)q * HW * NSL;
#pragma unroll
    for (int mi = 0; mi < 4; ++mi) {
#pragma unroll
        for (int ni = 0; ni < 4; ++ni) {
            const int j = n0 + wc * 64 + ni * 16 + lo;
            if (j >= NSL) continue;
#pragma unroll
            for (int r = 0; r < 4; ++r) {
                const int m = m0 + wr * 64 + mi * 16 + hi * 4 + r;
                if (m < HW) Sq[(size_t)m * NSL + j] = (f16)acc[mi][ni][r];
            }
        }
    }
}

// ---------------------------------------------------------------------------
// K3: fused softmaxes (S is fp16).
//   Blocks [0, 1225): Ts row softmax, WAVE-PER-ROW (4 rows/block, no
//     barriers) + fused class row-sums R.
//   Blocks [1225, 1225+NQ*16): Tq column softmax.
// ---------------------------------------------------------------------------
#define TSBLK (NQ * HW / 4)   // 1225
__global__ __launch_bounds__(256) void k_soft(const f16* __restrict__ S,
                                              bf16* __restrict__ Ts,
                                              bf16* __restrict__ Tq,
                                              float* __restrict__ R) {
    const int bid = blockIdx.x;
    if (bid < TSBLK) {
        // ---- Ts role: one WAVE per (q,m) row; no __syncthreads ----
        const int lane = threadIdx.x & 63, w = threadIdx.x >> 6;
        const int qm = bid * 4 + w;          // < 4900
        const int q = qm / HW, m = qm - q * HW;
        const f16* row = S + (size_t)qm * NSL;
        bf16* orow = Ts + ((size_t)q * RPQ + m) * NSLP;
        float x[16];
        float mx = -1e30f;
#pragma unroll
        for (int p = 0; p < 16; ++p) {
            int j = lane + p * 64;
            x[p] = (j < NSL) ? (float)row[j] : -1e30f;
            mx = fmaxf(mx, x[p]);
        }
        for (int d = 32; d; d >>= 1) mx = fmaxf(mx, __shfl_xor(mx, d));
        float sum = 0.f;
#pragma unroll
        for (int p = 0; p < 16; ++p) {
            x[p] = expf(GAMMA * (x[p] - mx));   // pads -> exp(-inf) = 0
            sum += x[p];
        }
        for (int d = 32; d; d >>= 1) sum += __shfl_xor(sum, d);
        const float inv = 1.f / sum;
        float racc[NWAY];
#pragma unroll
        for (int s = 0; s < NWAY; ++s) racc[s] = 0.f;
#pragma unroll
        for (int p = 0; p < 16; ++p) {
            int j = lane + p * 64;
            if (j < NSL) {
                float val = x[p] * inv;
                orow[j] = (bf16)val;
                int cls = j / HW;
#pragma unroll
                for (int s = 0; s < NWAY; ++s) racc[s] += (cls == s) ? val : 0.f;
            } else if (j < NSLP) {
                orow[j] = (bf16)0.f;   // zero K-pad
            }
        }
#pragma unroll
        for (int s = 0; s < NWAY; ++s)
            for (int d = 32; d; d >>= 1) racc[s] += __shfl_xor(racc[s], d);
        if (lane == 0) {
#pragma unroll
            for (int s = 0; s < NWAY; ++s)
                R[((size_t)q * NWAY + s) * HW + m] = racc[s];
        }
    } else {
        // ---- Tq role: 64 columns per block, 4 m-groups of 49 ----
        const int idx2 = bid - TSBLK;
        const int q  = idx2 >> 4;
        const int bx = idx2 & 15;
        const int tx = threadIdx.x & 63;
        const int tg = threadIdx.x >> 6;
        const int j  = bx * 64 + tx;
        const int m0 = tg * 49;
        const f16* base = S + (size_t)q * HW * NSL;
        bf16* ob = Tq + (size_t)q * RPQ * NSLP;
        __shared__ float rmax[4][64], rsum[4][64];
        float xv[49];
        float mx = -1e30f;
        if (j < NSL) {
#pragma unroll
            for (int i = 0; i < 49; ++i) {
                xv[i] = (float)base[(m0 + i) * NSL + j];
                mx = fmaxf(mx, xv[i]);
            }
        }
        rmax[tg][tx] = mx;
        __syncthreads();
        mx = fmaxf(fmaxf(rmax[0][tx], rmax[1][tx]), fmaxf(rmax[2][tx], rmax[3][tx]));
        float sum = 0.f;
        if (j < NSL) {
#pragma unroll
            for (int i = 0; i < 49; ++i) {
                xv[i] = expf(GAMMA2 * (xv[i] - mx));
                sum += xv[i];
            }
        }
        rsum[tg][tx] = sum;
        __syncthreads();
        const float inv = 1.f / (rsum[0][tx] + rsum[1][tx] + rsum[2][tx] + rsum[3][tx]);
        if (j < NSL) {
#pragma unroll
            for (int i = 0; i < 49; ++i) ob[(size_t)(m0 + i) * NSLP + j] = (bf16)(xv[i] * inv);
        } else if (j < NSLP) {
#pragma unroll
            for (int i = 0; i < 49; ++i) ob[(size_t)(m0 + i) * NSLP + j] = (bf16)0.f;
        }
    }
}

// ---------------------------------------------------------------------------
// K4: M = 0.25 * Tq (196x992) * Ts^T (992x196) -> bf16, row stride MST=200.
// grid (4 j, 4 i, 25 q), 64 threads, one wave per 64x64 tile (400 blocks --
// the measured-good wide form; LDS-tiled 100-block variant regressed r11).
// jt==0 blocks also compute rhs[q][i] = 1 + 0.5*rowsum(Tq[i][:]) for free.
// ---------------------------------------------------------------------------
__global__ __launch_bounds__(64) void k_mgemm(const bf16* __restrict__ Tq,
                                              const bf16* __restrict__ Ts,
                                              bf16* __restrict__ Mb,
                                              float* __restrict__ rhs) {
    const int q  = blockIdx.z;
    const int it = blockIdx.y;
    const int jt = blockIdx.x;
    const int l  = threadIdx.x;
    const int lo = l & 15, hi = l >> 4;
    const bool dorhs = (jt == 0);
    const bf16* Ap[4];
    const bf16* Bp[4];
#pragma unroll
    for (int mi = 0; mi < 4; ++mi)
        Ap[mi] = Tq + ((size_t)q * RPQ + it * 64 + mi * 16 + lo) * NSLP + hi * 8;
#pragma unroll
    for (int ni = 0; ni < 4; ++ni)
        Bp[ni] = Ts + ((size_t)q * RPQ + jt * 64 + ni * 16 + lo) * NSLP + hi * 8;

    f32x4 acc[4][4] = {};
    float rsum[4] = {0.f, 0.f, 0.f, 0.f};
#pragma unroll 2
    for (int k0 = 0; k0 < NSLP; k0 += 32) {
        bf16x8 a[4], b[4];
#pragma unroll
        for (int mi = 0; mi < 4; ++mi) a[mi] = *reinterpret_cast<const bf16x8*>(Ap[mi] + k0);
#pragma unroll
        for (int ni = 0; ni < 4; ++ni) b[ni] = *reinterpret_cast<const bf16x8*>(Bp[ni] + k0);
        if (dorhs) {
#pragma unroll
            for (int mi = 0; mi < 4; ++mi)
#pragma unroll
                for (int e = 0; e < 8; ++e) rsum[mi] += (float)a[mi][e];
        }
#pragma unroll
        for (int mi = 0; mi < 4; ++mi)
#pragma unroll
            for (int ni = 0; ni < 4; ++ni)
                acc[mi][ni] = __builtin_amdgcn_mfma_f32_16x16x32_bf16(a[mi], b[ni], acc[mi][ni], 0, 0, 0);
    }

    if (dorhs) {
#pragma unroll
        for (int mi = 0; mi < 4; ++mi) {
            float v = rsum[mi];
            v += __shfl_xor(v, 16);
            v += __shfl_xor(v, 32);   // summed over the 4 hi-slices
            const int i = it * 64 + mi * 16 + lo;
            if (hi == 0 && i < HW) rhs[q * HW + i] = 1.f + 0.5f * v;
        }
    }

    bf16* Mq = Mb + (size_t)q * MRA * MST;
#pragma unroll
    for (int mi = 0; mi < 4; ++mi) {
#pragma unroll
        for (int ni = 0; ni < 4; ++ni) {
            const int j = jt * 64 + ni * 16 + lo;
            if (j >= MST) continue;
#pragma unroll
            for (int r = 0; r < 4; ++r) {
                const int i = it * 64 + mi * 16 + hi * 4 + r;
                if (i >= MRA) continue;
                Mq[(size_t)i * MST + j] =
                    (i < HW && j < HW) ? (bf16)(0.25f * acc[mi][ni][r]) : (bf16)0.f;
            }
        }
    }
}

// ---------------------------------------------------------------------------
// K5: per-query Katz solve, 1024 threads (16 waves).  Minimal work:
//   - M (bf16, 78.4 KB) -> LDS; rhs read from global (precomputed by k_mgemm)
//   - NITER x (v <- rhs + M v): 4 col-quarters/row, LDS partial reduce
//   - out[q][s] = (R[s].v) / total
// ---------------------------------------------------------------------------
__global__ __launch_bounds__(1024) void k_solve2(const bf16* __restrict__ Mb,
                                                 const float* __restrict__ rhs,
                                                 const float* __restrict__ R,
                                                 float* __restrict__ out) {
    const int q = blockIdx.x;
    __shared__ __align__(16) bf16 Ms[HW * MST];            // 78,400 B
    __shared__ __align__(16) float va[MST], vb[MST];
    __shared__ float part[4][256];
    __shared__ float rhsl[HW];
    __shared__ float cls[NWAY];
    const int t = threadIdx.x, lane = t & 63, w = t >> 6;

    // --- M -> LDS (identical layout, contiguous bf16x8 copy) ---
    const bf16x8* gm = reinterpret_cast<const bf16x8*>(Mb + (size_t)q * MRA * MST);
    bf16x8* lm = reinterpret_cast<bf16x8*>(Ms);
    for (int i = t; i < HW * (MST / 8); i += 1024) lm[i] = gm[i];

    // --- rhs from global ---
    if (t < MST) {
        float r = (t < HW) ? rhs[q * HW + t] : 0.f;
        if (t < HW) rhsl[t] = r;
        va[t] = r; vb[t] = 0.f;
    }
    __syncthreads();

    // --- iterations ---
    const int r = t & 255, qd = t >> 8;
    const int cstart = (qd == 0) ? 0 : 7 + 6 * (qd - 1);   // {0,7,13,19}
    const int ccnt   = (qd == 0) ? 7 : 6;                  // 25 chunks = 200 cols
    for (int it = 0; it < NITER; ++it) {
        const float* src = (it & 1) ? vb : va;
        float* dst = (it & 1) ? va : vb;
        float a = 0.f;
        if (r < HW) {
            const bf16x8* mrow = reinterpret_cast<const bf16x8*>(&Ms[r * MST]);
            for (int c = cstart; c < cstart + ccnt; ++c) {
                bf16x8 mv = mrow[c];
                const float* sp = &src[c * 8];
#pragma unroll
                for (int e = 0; e < 8; ++e) a += (float)mv[e] * sp[e];
            }
        }
        part[qd][r] = a;
        __syncthreads();
        if (qd == 0 && r < HW)
            dst[r] = rhsl[r] + (part[0][r] + part[1][r] + part[2][r] + part[3][r]);
        __syncthreads();
    }
    // NITER even -> final v in va

    if (w < NWAY) {
        const float* Rs = R + ((size_t)q * NWAY + w) * HW;
        float a = 0.f;
        for (int m = lane; m < HW; m += 64) a += va[m] * Rs[m];
        for (int d = 32; d; d >>= 1) a += __shfl_xor(a, d);
        if (lane == 0) cls[w] = a;
    }
    __syncthreads();
    if (t == 0) {
        float tot = cls[0] + cls[1] + cls[2] + cls[3] + cls[4];
        float invt = 1.f / tot;
        for (int s = 0; s < NWAY; ++s) out[q * NWAY + s] = cls[s] * invt;
    }
}

// ---------------------------------------------------------------------------
extern "C" void kernel_launch(void* const* d_in, const int* in_sizes, int n_in,
                              void* d_out, int out_size, void* d_ws, size_t ws_size,
                              hipStream_t stream) {
    const float* feat = (const float*)d_in[0];
    float* out = (float*)d_out;
    char* w = (char*)d_ws;

    // workspace layout (16B-aligned)
    f16*   S    = (f16*)w;    w += sizeof(f16)   * (size_t)NQ * HW * NSL;   //  9.61 MB
    bf16*  Ts   = (bf16*)w;   w += sizeof(bf16)  * (size_t)NQ * RPQ * NSLP; // 10.32 MB
    bf16*  Tq   = (bf16*)w;   w += sizeof(bf16)  * (size_t)NQ * RPQ * NSLP; // 10.32 MB
    bf16*  qnbt = (bf16*)w;   w += sizeof(bf16)  * (size_t)NQ * RPQ * CC;   //  6.66 MB
    bf16*  snbt = (bf16*)w;   w += sizeof(bf16)  * (size_t)BROWS * CC;      //  1.31 MB
    float* R    = (float*)w;  w += sizeof(float) * (size_t)NQ * NWAY * HW;
    float* rhs  = (float*)w;  w += sizeof(float) * (size_t)NQ * HW;
    // S is dead after both softmaxes -> bf16 M aliases it (2.08 MB <= 9.6 MB)
    bf16* Mb = (bf16*)S;

    k_norm  <<<dim3(13, NQ + NWAY), 256, 0, stream>>>(feat, qnbt, snbt);
    k_sgemm <<<dim3(8, 2, NQ), 256, 0, stream>>>(qnbt, snbt, S);
    k_soft  <<<TSBLK + NQ * 16, 256, 0, stream>>>(S, Ts, Tq, R);
    k_mgemm <<<dim3(4, 4, NQ), 64, 0, stream>>>(Tq, Ts, Mb, rhs);
    k_solve2<<<NQ, 1024, 0, stream>>>(Mb, rhs, R, out);
}

// Round 15
// 88.112 us; speedup vs baseline: 1.2602x; 1.0290x over previous
//
#include <hip/hip_runtime.h>
#include <math.h>

// Problem constants
#define NQ     25      // number of query images (= n_support)
#define NWAY   5
#define KSHOT  5
#define CC     640     // channels (k-dim of S gemm; 640 = 20*32)
#define HW     196     // 14*14
#define NSL    980     // NWAY*HW support locations
#define NSLP   992     // padded K for M-gemm (31*32)
#define RPQ    208     // padded row count per query (13*16)
#define BROWS  1024    // snbt allocated rows (8 n-tiles of 128)
#define MST    200     // M row stride in bf16 (400B, 16B-aligned; 25 bf16x8 chunks)
#define MRA    208     // M allocated rows per query
#define GAMMA  20.0f
#define GAMMA2 10.0f
#define NITER  4       // ||M||_1 = 0.25 -> tail 0.25^5/0.75 ~ 1.3e-3 vs threshold 1.77e-2

typedef __bf16 bf16;
typedef _Float16 f16;
typedef __attribute__((ext_vector_type(8))) __bf16 bf16x8;
typedef __attribute__((ext_vector_type(4))) float f32x4;

// ---------------------------------------------------------------------------
// K1: prototype mean + per-location L2 normalization -> TRANSPOSED bf16.
// float4-vectorized over locations: thread = (location-quad qd, 10-ch group).
// ---------------------------------------------------------------------------
__global__ __launch_bounds__(256) void k_norm(const float* __restrict__ feat,
                                              bf16* __restrict__ qnbt,
                                              bf16* __restrict__ snbt) {
    const int by = blockIdx.y;
    const int t  = threadIdx.x;
    const int qd = t & 3;                     // location quad within 16-loc tile
    const int cg = t >> 2;                    // 64 channel groups of 10
    const int l0 = blockIdx.x * 16 + qd * 4;  // first of this thread's 4 locations
    const bool act = (l0 < HW);
    const int c0 = cg * 10;
    const int w  = t >> 6, lane = t & 63;
    __shared__ float4 pr2[4][4];              // [wave][qd] partial sums

    float4 xv[10];
    float4 ss = {0.f, 0.f, 0.f, 0.f};
    if (by < NQ) {
        const float* f = feat + (size_t)(NQ + by) * CC * HW;
        if (act) {
#pragma unroll
            for (int i = 0; i < 10; ++i) {
                float4 v = *reinterpret_cast<const float4*>(&f[(c0 + i) * HW + l0]);
                xv[i] = v;
                ss.x += v.x * v.x; ss.y += v.y * v.y;
                ss.z += v.z * v.z; ss.w += v.w * v.w;
            }
        }
    } else {
        const int s = by - NQ;
        const float* f = feat + (size_t)(NQ + s * KSHOT) * CC * HW;
        const size_t img = (size_t)CC * HW;
        if (act) {
#pragma unroll
            for (int i = 0; i < 10; ++i) {
                const float* p = &f[(c0 + i) * HW + l0];
                float4 v0 = *reinterpret_cast<const float4*>(p);
                float4 v1 = *reinterpret_cast<const float4*>(p + img);
                float4 v2 = *reinterpret_cast<const float4*>(p + 2 * img);
                float4 v3 = *reinterpret_cast<const float4*>(p + 3 * img);
                float4 v4 = *reinterpret_cast<const float4*>(p + 4 * img);
                float4 m;
                m.x = 0.2f * (v0.x + v1.x + v2.x + v3.x + v4.x);
                m.y = 0.2f * (v0.y + v1.y + v2.y + v3.y + v4.y);
                m.z = 0.2f * (v0.z + v1.z + v2.z + v3.z + v4.z);
                m.w = 0.2f * (v0.w + v1.w + v2.w + v3.w + v4.w);
                xv[i] = m;
                ss.x += m.x * m.x; ss.y += m.y * m.y;
                ss.z += m.z * m.z; ss.w += m.w * m.w;
            }
        }
    }
    // reduce over the 16 cg's within each wave (lane bits 2..5)
#pragma unroll
    for (int d = 4; d <= 32; d <<= 1) {
        ss.x += __shfl_xor(ss.x, d);
        ss.y += __shfl_xor(ss.y, d);
        ss.z += __shfl_xor(ss.z, d);
        ss.w += __shfl_xor(ss.w, d);
    }
    if (lane < 4) pr2[w][lane] = ss;          // lane == qd for lanes 0..3
    __syncthreads();
    const float4 s0 = pr2[0][qd], s1 = pr2[1][qd], s2 = pr2[2][qd], s3 = pr2[3][qd];
    float4 inv;
    inv.x = 1.f / (1e-16f + sqrtf(s0.x + s1.x + s2.x + s3.x));
    inv.y = 1.f / (1e-16f + sqrtf(s0.y + s1.y + s2.y + s3.y));
    inv.z = 1.f / (1e-16f + sqrtf(s0.z + s1.z + s2.z + s3.z));
    inv.w = 1.f / (1e-16f + sqrtf(s0.w + s1.w + s2.w + s3.w));
    if (act) {
        bf16* base = (by < NQ) ? (qnbt + ((size_t)by * RPQ + l0) * CC)
                               : (snbt + ((size_t)(by - NQ) * HW + l0) * CC);
#pragma unroll
        for (int i = 0; i < 10; ++i) {
            base[(size_t)0 * CC + c0 + i] = (bf16)(xv[i].x * inv.x);
            base[(size_t)1 * CC + c0 + i] = (bf16)(xv[i].y * inv.y);
            base[(size_t)2 * CC + c0 + i] = (bf16)(xv[i].z * inv.z);
            base[(size_t)3 * CC + c0 + i] = (bf16)(xv[i].w * inv.w);
        }
    }
}

// ---------------------------------------------------------------------------
// K2: S[q][m][j] = sum_c qnbt[q][m][c] * snbt[j][c]  -- LDS-tiled MFMA GEMM.
// 128x128 tile, BK=64 (10 k-steps, 2 MFMA sub-steps each), 256 threads =
// 4 waves (2x2), each wave 64x64 (4x4 of 16x16).  m-tiles rows {0, 80}
// (overlap written twice, identical values). grid (8 n, 2 m, 25 q).
// S stored as fp16 (fp32 accum, one rounding on store).
// ---------------------------------------------------------------------------
#define ASTR2 72   // LDS row stride in bf16 (144B): 2-way bank alias only
__global__ __launch_bounds__(256) void k_sgemm(const bf16* __restrict__ qnbt,
                                               const bf16* __restrict__ snbt,
                                               f16* __restrict__ S) {
    const int q  = blockIdx.z;
    const int m0 = blockIdx.y * 80;          // {0, 80}
    const int n0 = blockIdx.x * 128;         // 0..896
    __shared__ bf16 As[128 * ASTR2];
    __shared__ bf16 Bs[128 * ASTR2];
    const int t = threadIdx.x;
    const int lane = t & 63, w = t >> 6;
    const int wr = w >> 1, wc = w & 1;
    const int lo = lane & 15, hi = lane >> 4;
    const int sr = t >> 1, sh = (t & 1) * 32;   // stage: row, col-half (bf16)

    const bf16* Aq = qnbt + (size_t)q * RPQ * CC;
    f32x4 acc[4][4] = {};

    for (int k0 = 0; k0 < CC; k0 += 64) {
        bf16x8 a0 = *reinterpret_cast<const bf16x8*>(&Aq[(size_t)(m0 + sr) * CC + k0 + sh]);
        bf16x8 a1 = *reinterpret_cast<const bf16x8*>(&Aq[(size_t)(m0 + sr) * CC + k0 + sh + 8]);
        bf16x8 a2 = *reinterpret_cast<const bf16x8*>(&Aq[(size_t)(m0 + sr) * CC + k0 + sh + 16]);
        bf16x8 a3 = *reinterpret_cast<const bf16x8*>(&Aq[(size_t)(m0 + sr) * CC + k0 + sh + 24]);
        bf16x8 b0 = *reinterpret_cast<const bf16x8*>(&snbt[(size_t)(n0 + sr) * CC + k0 + sh]);
        bf16x8 b1 = *reinterpret_cast<const bf16x8*>(&snbt[(size_t)(n0 + sr) * CC + k0 + sh + 8]);
        bf16x8 b2 = *reinterpret_cast<const bf16x8*>(&snbt[(size_t)(n0 + sr) * CC + k0 + sh + 16]);
        bf16x8 b3 = *reinterpret_cast<const bf16x8*>(&snbt[(size_t)(n0 + sr) * CC + k0 + sh + 24]);
        __syncthreads();   // previous step's fragment reads done
        *reinterpret_cast<bf16x8*>(&As[sr * ASTR2 + sh])      = a0;
        *reinterpret_cast<bf16x8*>(&As[sr * ASTR2 + sh + 8])  = a1;
        *reinterpret_cast<bf16x8*>(&As[sr * ASTR2 + sh + 16]) = a2;
        *reinterpret_cast<bf16x8*>(&As[sr * ASTR2 + sh + 24]) = a3;
        *reinterpret_cast<bf16x8*>(&Bs[sr * ASTR2 + sh])      = b0;
        *reinterpret_cast<bf16x8*>(&Bs[sr * ASTR2 + sh + 8])  = b1;
        *reinterpret_cast<bf16x8*>(&Bs[sr * ASTR2 + sh + 16]) = b2;
        *reinterpret_cast<bf16x8*>(&Bs[sr * ASTR2 + sh + 24]) = b3;
        __syncthreads();
#pragma unroll
        for (int kk = 0; kk < 2; ++kk) {
            bf16x8 af[4], bf[4];
#pragma unroll
            for (int mi = 0; mi < 4; ++mi)
                af[mi] = *reinterpret_cast<const bf16x8*>(
                    &As[(wr * 64 + mi * 16 + lo) * ASTR2 + kk * 32 + hi * 8]);
#pragma unroll
            for (int ni = 0; ni < 4; ++ni)
                bf[ni] = *reinterpret_cast<const bf16x8*>(
                    &Bs[(wc * 64 + ni * 16 + lo) * ASTR2 + kk * 32 + hi * 8]);
#pragma unroll
            for (int mi = 0; mi < 4; ++mi)
#pragma unroll
                for (int ni = 0; ni < 4; ++ni)
                    acc[mi][ni] = __builtin_amdgcn_mfma_f32_16x16x32_bf16(af[mi], bf[ni], acc[mi][ni], 0, 0, 0);
        }
    }

    f16* Sq = S + (size_t)q * HW * NSL;
#pragma unroll
    for (int mi = 0; mi < 4; ++mi) {
#pragma unroll
        for (int ni = 0; ni < 4; ++ni) {
            const int j = n0 + wc * 64 + ni * 16 + lo;
            if (j >= NSL) continue;
#pragma unroll
            for (int r = 0; r < 4; ++r) {
                const int m = m0 + wr * 64 + mi * 16 + hi * 4 + r;
                if (m < HW) Sq[(size_t)m * NSL + j] = (f16)acc[mi][ni][r];
            }
        }
    }
}

// ---------------------------------------------------------------------------
// K3: fused softmaxes (S is fp16).
//   Blocks [0, 1225): Ts row softmax, WAVE-PER-ROW (4 rows/block, no
//     barriers) + fused class row-sums R.
//   Blocks [1225, 1225+NQ*16): Tq column softmax.
// ---------------------------------------------------------------------------
#define TSBLK (NQ * HW / 4)   // 1225
__global__ __launch_bounds__(256) void k_soft(const f16* __restrict__ S,
                                              bf16* __restrict__ Ts,
                                              bf16* __restrict__ Tq,
                                              float* __restrict__ R) {
    const int bid = blockIdx.x;
    if (bid < TSBLK) {
        // ---- Ts role: one WAVE per (q,m) row; no __syncthreads ----
        const int lane = threadIdx.x & 63, w = threadIdx.x >> 6;
        const int qm = bid * 4 + w;          // < 4900
        const int q = qm / HW, m = qm - q * HW;
        const f16* row = S + (size_t)qm * NSL;
        bf16* orow = Ts + ((size_t)q * RPQ + m) * NSLP;
        float x[16];
        float mx = -1e30f;
#pragma unroll
        for (int p = 0; p < 16; ++p) {
            int j = lane + p * 64;
            x[p] = (j < NSL) ? (float)row[j] : -1e30f;
            mx = fmaxf(mx, x[p]);
        }
        for (int d = 32; d; d >>= 1) mx = fmaxf(mx, __shfl_xor(mx, d));
        float sum = 0.f;
#pragma unroll
        for (int p = 0; p < 16; ++p) {
            x[p] = expf(GAMMA * (x[p] - mx));   // pads -> exp(-inf) = 0
            sum += x[p];
        }
        for (int d = 32; d; d >>= 1) sum += __shfl_xor(sum, d);
        const float inv = 1.f / sum;
        float racc[NWAY];
#pragma unroll
        for (int s = 0; s < NWAY; ++s) racc[s] = 0.f;
#pragma unroll
        for (int p = 0; p < 16; ++p) {
            int j = lane + p * 64;
            if (j < NSL) {
                float val = x[p] * inv;
                orow[j] = (bf16)val;
                int cls = j / HW;
#pragma unroll
                for (int s = 0; s < NWAY; ++s) racc[s] += (cls == s) ? val : 0.f;
            } else if (j < NSLP) {
                orow[j] = (bf16)0.f;   // zero K-pad
            }
        }
#pragma unroll
        for (int s = 0; s < NWAY; ++s)
            for (int d = 32; d; d >>= 1) racc[s] += __shfl_xor(racc[s], d);
        if (lane == 0) {
#pragma unroll
            for (int s = 0; s < NWAY; ++s)
                R[((size_t)q * NWAY + s) * HW + m] = racc[s];
        }
    } else {
        // ---- Tq role: 64 columns per block, 4 m-groups of 49 ----
        const int idx2 = bid - TSBLK;
        const int q  = idx2 >> 4;
        const int bx = idx2 & 15;
        const int tx = threadIdx.x & 63;
        const int tg = threadIdx.x >> 6;
        const int j  = bx * 64 + tx;
        const int m0 = tg * 49;
        const f16* base = S + (size_t)q * HW * NSL;
        bf16* ob = Tq + (size_t)q * RPQ * NSLP;
        __shared__ float rmax[4][64], rsum[4][64];
        float xv[49];
        float mx = -1e30f;
        if (j < NSL) {
#pragma unroll
            for (int i = 0; i < 49; ++i) {
                xv[i] = (float)base[(m0 + i) * NSL + j];
                mx = fmaxf(mx, xv[i]);
            }
        }
        rmax[tg][tx] = mx;
        __syncthreads();
        mx = fmaxf(fmaxf(rmax[0][tx], rmax[1][tx]), fmaxf(rmax[2][tx], rmax[3][tx]));
        float sum = 0.f;
        if (j < NSL) {
#pragma unroll
            for (int i = 0; i < 49; ++i) {
                xv[i] = expf(GAMMA2 * (xv[i] - mx));
                sum += xv[i];
            }
        }
        rsum[tg][tx] = sum;
        __syncthreads();
        const float inv = 1.f / (rsum[0][tx] + rsum[1][tx] + rsum[2][tx] + rsum[3][tx]);
        if (j < NSL) {
#pragma unroll
            for (int i = 0; i < 49; ++i) ob[(size_t)(m0 + i) * NSLP + j] = (bf16)(xv[i] * inv);
        } else if (j < NSLP) {
#pragma unroll
            for (int i = 0; i < 49; ++i) ob[(size_t)(m0 + i) * NSLP + j] = (bf16)0.f;
        }
    }
}

// ---------------------------------------------------------------------------
// K4: M = 0.25 * Tq (196x992) * Ts^T (992x196) -> bf16, row stride MST=200.
// grid (4 j, 4 i, 25 q), 64 threads, one wave per 64x64 tile (400 blocks --
// the measured-good wide form).  Unroll 4: more loads in flight per wave
// (latency-bound kernel).  jt==0 blocks also compute rhs for free.
// ---------------------------------------------------------------------------
__global__ __launch_bounds__(64) void k_mgemm(const bf16* __restrict__ Tq,
                                              const bf16* __restrict__ Ts,
                                              bf16* __restrict__ Mb,
                                              float* __restrict__ rhs) {
    const int q  = blockIdx.z;
    const int it = blockIdx.y;
    const int jt = blockIdx.x;
    const int l  = threadIdx.x;
    const int lo = l & 15, hi = l >> 4;
    const bool dorhs = (jt == 0);
    const bf16* Ap[4];
    const bf16* Bp[4];
#pragma unroll
    for (int mi = 0; mi < 4; ++mi)
        Ap[mi] = Tq + ((size_t)q * RPQ + it * 64 + mi * 16 + lo) * NSLP + hi * 8;
#pragma unroll
    for (int ni = 0; ni < 4; ++ni)
        Bp[ni] = Ts + ((size_t)q * RPQ + jt * 64 + ni * 16 + lo) * NSLP + hi * 8;

    f32x4 acc[4][4] = {};
    float rsum[4] = {0.f, 0.f, 0.f, 0.f};
#pragma unroll 4
    for (int k0 = 0; k0 < NSLP; k0 += 32) {
        bf16x8 a[4], b[4];
#pragma unroll
        for (int mi = 0; mi < 4; ++mi) a[mi] = *reinterpret_cast<const bf16x8*>(Ap[mi] + k0);
#pragma unroll
        for (int ni = 0; ni < 4; ++ni) b[ni] = *reinterpret_cast<const bf16x8*>(Bp[ni] + k0);
        if (dorhs) {
#pragma unroll
            for (int mi = 0; mi < 4; ++mi)
#pragma unroll
                for (int e = 0; e < 8; ++e) rsum[mi] += (float)a[mi][e];
        }
#pragma unroll
        for (int mi = 0; mi < 4; ++mi)
#pragma unroll
            for (int ni = 0; ni < 4; ++ni)
                acc[mi][ni] = __builtin_amdgcn_mfma_f32_16x16x32_bf16(a[mi], b[ni], acc[mi][ni], 0, 0, 0);
    }

    if (dorhs) {
#pragma unroll
        for (int mi = 0; mi < 4; ++mi) {
            float v = rsum[mi];
            v += __shfl_xor(v, 16);
            v += __shfl_xor(v, 32);   // summed over the 4 hi-slices
            const int i = it * 64 + mi * 16 + lo;
            if (hi == 0 && i < HW) rhs[q * HW + i] = 1.f + 0.5f * v;
        }
    }

    bf16* Mq = Mb + (size_t)q * MRA * MST;
#pragma unroll
    for (int mi = 0; mi < 4; ++mi) {
#pragma unroll
        for (int ni = 0; ni < 4; ++ni) {
            const int j = jt * 64 + ni * 16 + lo;
            if (j >= MST) continue;
#pragma unroll
            for (int r = 0; r < 4; ++r) {
                const int i = it * 64 + mi * 16 + hi * 4 + r;
                if (i >= MRA) continue;
                Mq[(size_t)i * MST + j] =
                    (i < HW && j < HW) ? (bf16)(0.25f * acc[mi][ni][r]) : (bf16)0.f;
            }
        }
    }
}

// ---------------------------------------------------------------------------
// K5: per-query Katz solve, 1024 threads (16 waves).  Minimal work:
//   - M (bf16, 78.4 KB) -> LDS; rhs read from global (precomputed by k_mgemm)
//   - NITER x (v <- rhs + M v): 4 col-quarters/row, LDS partial reduce
//   - out[q][s] = (R[s].v) / total
// ---------------------------------------------------------------------------
__global__ __launch_bounds__(1024) void k_solve2(const bf16* __restrict__ Mb,
                                                 const float* __restrict__ rhs,
                                                 const float* __restrict__ R,
                                                 float* __restrict__ out) {
    const int q = blockIdx.x;
    __shared__ __align__(16) bf16 Ms[HW * MST];            // 78,400 B
    __shared__ __align__(16) float va[MST], vb[MST];
    __shared__ float part[4][256];
    __shared__ float rhsl[HW];
    __shared__ float cls[NWAY];
    const int t = threadIdx.x, lane = t & 63, w = t >> 6;

    // --- M -> LDS (identical layout, contiguous bf16x8 copy) ---
    const bf16x8* gm = reinterpret_cast<const bf16x8*>(Mb + (size_t)q * MRA * MST);
    bf16x8* lm = reinterpret_cast<bf16x8*>(Ms);
    for (int i = t; i < HW * (MST / 8); i += 1024) lm[i] = gm[i];

    // --- rhs from global ---
    if (t < MST) {
        float r = (t < HW) ? rhs[q * HW + t] : 0.f;
        if (t < HW) rhsl[t] = r;
        va[t] = r; vb[t] = 0.f;
    }
    __syncthreads();

    // --- iterations ---
    const int r = t & 255, qd = t >> 8;
    const int cstart = (qd == 0) ? 0 : 7 + 6 * (qd - 1);   // {0,7,13,19}
    const int ccnt   = (qd == 0) ? 7 : 6;                  // 25 chunks = 200 cols
    for (int it = 0; it < NITER; ++it) {
        const float* src = (it & 1) ? vb : va;
        float* dst = (it & 1) ? va : vb;
        float a = 0.f;
        if (r < HW) {
            const bf16x8* mrow = reinterpret_cast<const bf16x8*>(&Ms[r * MST]);
            for (int c = cstart; c < cstart + ccnt; ++c) {
                bf16x8 mv = mrow[c];
                const float* sp = &src[c * 8];
#pragma unroll
                for (int e = 0; e < 8; ++e) a += (float)mv[e] * sp[e];
            }
        }
        part[qd][r] = a;
        __syncthreads();
        if (qd == 0 && r < HW)
            dst[r] = rhsl[r] + (part[0][r] + part[1][r] + part[2][r] + part[3][r]);
        __syncthreads();
    }
    // NITER even -> final v in va

    if (w < NWAY) {
        const float* Rs = R + ((size_t)q * NWAY + w) * HW;
        float a = 0.f;
        for (int m = lane; m < HW; m += 64) a += va[m] * Rs[m];
        for (int d = 32; d; d >>= 1) a += __shfl_xor(a, d);
        if (lane == 0) cls[w] = a;
    }
    __syncthreads();
    if (t == 0) {
        float tot = cls[0] + cls[1] + cls[2] + cls[3] + cls[4];
        float invt = 1.f / tot;
        for (int s = 0; s < NWAY; ++s) out[q * NWAY + s] = cls[s] * invt;
    }
}

// ---------------------------------------------------------------------------
extern "C" void kernel_launch(void* const* d_in, const int* in_sizes, int n_in,
                              void* d_out, int out_size, void* d_ws, size_t ws_size,
                              hipStream_t stream) {
    const float* feat = (const float*)d_in[0];
    float* out = (float*)d_out;
    char* w = (char*)d_ws;

    // workspace layout (16B-aligned)
    f16*   S    = (f16*)w;    w += sizeof(f16)   * (size_t)NQ * HW * NSL;   //  9.61 MB
    bf16*  Ts   = (bf16*)w;   w += sizeof(bf16)  * (size_t)NQ * RPQ * NSLP; // 10.32 MB
    bf16*  Tq   = (bf16*)w;   w += sizeof(bf16)  * (size_t)NQ * RPQ * NSLP; // 10.32 MB
    bf16*  qnbt = (bf16*)w;   w += sizeof(bf16)  * (size_t)NQ * RPQ * CC;   //  6.66 MB
    bf16*  snbt = (bf16*)w;   w += sizeof(bf16)  * (size_t)BROWS * CC;      //  1.31 MB
    float* R    = (float*)w;  w += sizeof(float) * (size_t)NQ * NWAY * HW;
    float* rhs  = (float*)w;  w += sizeof(float) * (size_t)NQ * HW;
    // S is dead after both softmaxes -> bf16 M aliases it (2.08 MB <= 9.6 MB)
    bf16* Mb = (bf16*)S;

    k_norm  <<<dim3(13, NQ + NWAY), 256, 0, stream>>>(feat, qnbt, snbt);
    k_sgemm <<<dim3(8, 2, NQ), 256, 0, stream>>>(qnbt, snbt, S);
    k_soft  <<<TSBLK + NQ * 16, 256, 0, stream>>>(S, Ts, Tq, R);
    k_mgemm <<<dim3(4, 4, NQ), 64, 0, stream>>>(Tq, Ts, Mb, rhs);
    k_solve2<<<NQ, 1024, 0, stream>>>(Mb, rhs, R, out);
}

// Round 16
// 86.524 us; speedup vs baseline: 1.2833x; 1.0183x over previous
//
#include <hip/hip_runtime.h>
#include <math.h>

// Problem constants
#define NQ     25      // number of query images (= n_support)
#define NWAY   5
#define KSHOT  5
#define CC     640     // channels (k-dim of S gemm; 640 = 20*32)
#define HW     196     // 14*14
#define NSL    980     // NWAY*HW support locations
#define NSLP   992     // padded K for M-gemm (31*32)
#define RPQ    208     // padded row count per query (13*16)
#define BROWS  1024    // snbt allocated rows (8 n-tiles of 128)
#define MST    200     // M row stride in bf16 (400B, 16B-aligned; 25 bf16x8 chunks)
#define MRA    208     // M allocated rows per query
#define GAMMA  20.0f
#define GAMMA2 10.0f
#define NITER  4       // ||M||_1 = 0.25 -> tail 0.25^5/0.75 ~ 1.3e-3 vs threshold 1.77e-2

typedef __bf16 bf16;
typedef _Float16 f16;
typedef __attribute__((ext_vector_type(8))) __bf16 bf16x8;
typedef __attribute__((ext_vector_type(4))) float f32x4;

// ---------------------------------------------------------------------------
// K1: prototype mean + per-location L2 normalization -> TRANSPOSED bf16.
// float4-vectorized over locations: thread = (location-quad qd, 10-ch group).
// ---------------------------------------------------------------------------
__global__ __launch_bounds__(256) void k_norm(const float* __restrict__ feat,
                                              bf16* __restrict__ qnbt,
                                              bf16* __restrict__ snbt) {
    const int by = blockIdx.y;
    const int t  = threadIdx.x;
    const int qd = t & 3;                     // location quad within 16-loc tile
    const int cg = t >> 2;                    // 64 channel groups of 10
    const int l0 = blockIdx.x * 16 + qd * 4;  // first of this thread's 4 locations
    const bool act = (l0 < HW);
    const int c0 = cg * 10;
    const int w  = t >> 6, lane = t & 63;
    __shared__ float4 pr2[4][4];              // [wave][qd] partial sums

    float4 xv[10];
    float4 ss = {0.f, 0.f, 0.f, 0.f};
    if (by < NQ) {
        const float* f = feat + (size_t)(NQ + by) * CC * HW;
        if (act) {
#pragma unroll
            for (int i = 0; i < 10; ++i) {
                float4 v = *reinterpret_cast<const float4*>(&f[(c0 + i) * HW + l0]);
                xv[i] = v;
                ss.x += v.x * v.x; ss.y += v.y * v.y;
                ss.z += v.z * v.z; ss.w += v.w * v.w;
            }
        }
    } else {
        const int s = by - NQ;
        const float* f = feat + (size_t)(NQ + s * KSHOT) * CC * HW;
        const size_t img = (size_t)CC * HW;
        if (act) {
#pragma unroll
            for (int i = 0; i < 10; ++i) {
                const float* p = &f[(c0 + i) * HW + l0];
                float4 v0 = *reinterpret_cast<const float4*>(p);
                float4 v1 = *reinterpret_cast<const float4*>(p + img);
                float4 v2 = *reinterpret_cast<const float4*>(p + 2 * img);
                float4 v3 = *reinterpret_cast<const float4*>(p + 3 * img);
                float4 v4 = *reinterpret_cast<const float4*>(p + 4 * img);
                float4 m;
                m.x = 0.2f * (v0.x + v1.x + v2.x + v3.x + v4.x);
                m.y = 0.2f * (v0.y + v1.y + v2.y + v3.y + v4.y);
                m.z = 0.2f * (v0.z + v1.z + v2.z + v3.z + v4.z);
                m.w = 0.2f * (v0.w + v1.w + v2.w + v3.w + v4.w);
                xv[i] = m;
                ss.x += m.x * m.x; ss.y += m.y * m.y;
                ss.z += m.z * m.z; ss.w += m.w * m.w;
            }
        }
    }
    // reduce over the 16 cg's within each wave (lane bits 2..5)
#pragma unroll
    for (int d = 4; d <= 32; d <<= 1) {
        ss.x += __shfl_xor(ss.x, d);
        ss.y += __shfl_xor(ss.y, d);
        ss.z += __shfl_xor(ss.z, d);
        ss.w += __shfl_xor(ss.w, d);
    }
    if (lane < 4) pr2[w][lane] = ss;          // lane == qd for lanes 0..3
    __syncthreads();
    const float4 s0 = pr2[0][qd], s1 = pr2[1][qd], s2 = pr2[2][qd], s3 = pr2[3][qd];
    float4 inv;
    inv.x = 1.f / (1e-16f + sqrtf(s0.x + s1.x + s2.x + s3.x));
    inv.y = 1.f / (1e-16f + sqrtf(s0.y + s1.y + s2.y + s3.y));
    inv.z = 1.f / (1e-16f + sqrtf(s0.z + s1.z + s2.z + s3.z));
    inv.w = 1.f / (1e-16f + sqrtf(s0.w + s1.w + s2.w + s3.w));
    if (act) {
        bf16* base = (by < NQ) ? (qnbt + ((size_t)by * RPQ + l0) * CC)
                               : (snbt + ((size_t)(by - NQ) * HW + l0) * CC);
#pragma unroll
        for (int i = 0; i < 10; ++i) {
            base[(size_t)0 * CC + c0 + i] = (bf16)(xv[i].x * inv.x);
            base[(size_t)1 * CC + c0 + i] = (bf16)(xv[i].y * inv.y);
            base[(size_t)2 * CC + c0 + i] = (bf16)(xv[i].z * inv.z);
            base[(size_t)3 * CC + c0 + i] = (bf16)(xv[i].w * inv.w);
        }
    }
}

// ---------------------------------------------------------------------------
// K2: S[q][m][j] = sum_c qnbt[q][m][c] * snbt[j][c]  -- LDS-tiled MFMA GEMM.
// 128x128 tile, BK=64 (10 k-steps, 2 MFMA sub-steps each), 256 threads =
// 4 waves (2x2), each wave 64x64 (4x4 of 16x16).  m-tiles rows {0, 80}
// (overlap written twice, identical values). grid (8 n, 2 m, 25 q).
// S stored as fp16 (fp32 accum, one rounding on store).
// ---------------------------------------------------------------------------
#define ASTR2 72   // LDS row stride in bf16 (144B): 2-way bank alias only
__global__ __launch_bounds__(256) void k_sgemm(const bf16* __restrict__ qnbt,
                                               const bf16* __restrict__ snbt,
                                               f16* __restrict__ S) {
    const int q  = blockIdx.z;
    const int m0 = blockIdx.y * 80;          // {0, 80}
    const int n0 = blockIdx.x * 128;         // 0..896
    __shared__ bf16 As[128 * ASTR2];
    __shared__ bf16 Bs[128 * ASTR2];
    const int t = threadIdx.x;
    const int lane = t & 63, w = t >> 6;
    const int wr = w >> 1, wc = w & 1;
    const int lo = lane & 15, hi = lane >> 4;
    const int sr = t >> 1, sh = (t & 1) * 32;   // stage: row, col-half (bf16)

    const bf16* Aq = qnbt + (size_t)q * RPQ * CC;
    f32x4 acc[4][4] = {};

    for (int k0 = 0; k0 < CC; k0 += 64) {
        bf16x8 a0 = *reinterpret_cast<const bf16x8*>(&Aq[(size_t)(m0 + sr) * CC + k0 + sh]);
        bf16x8 a1 = *reinterpret_cast<const bf16x8*>(&Aq[(size_t)(m0 + sr) * CC + k0 + sh + 8]);
        bf16x8 a2 = *reinterpret_cast<const bf16x8*>(&Aq[(size_t)(m0 + sr) * CC + k0 + sh + 16]);
        bf16x8 a3 = *reinterpret_cast<const bf16x8*>(&Aq[(size_t)(m0 + sr) * CC + k0 + sh + 24]);
        bf16x8 b0 = *reinterpret_cast<const bf16x8*>(&snbt[(size_t)(n0 + sr) * CC + k0 + sh]);
        bf16x8 b1 = *reinterpret_cast<const bf16x8*>(&snbt[(size_t)(n0 + sr) * CC + k0 + sh + 8]);
        bf16x8 b2 = *reinterpret_cast<const bf16x8*>(&snbt[(size_t)(n0 + sr) * CC + k0 + sh + 16]);
        bf16x8 b3 = *reinterpret_cast<const bf16x8*>(&snbt[(size_t)(n0 + sr) * CC + k0 + sh + 24]);
        __syncthreads();   // previous step's fragment reads done
        *reinterpret_cast<bf16x8*>(&As[sr * ASTR2 + sh])      = a0;
        *reinterpret_cast<bf16x8*>(&As[sr * ASTR2 + sh + 8])  = a1;
        *reinterpret_cast<bf16x8*>(&As[sr * ASTR2 + sh + 16]) = a2;
        *reinterpret_cast<bf16x8*>(&As[sr * ASTR2 + sh + 24]) = a3;
        *reinterpret_cast<bf16x8*>(&Bs[sr * ASTR2 + sh])      = b0;
        *reinterpret_cast<bf16x8*>(&Bs[sr * ASTR2 + sh + 8])  = b1;
        *reinterpret_cast<bf16x8*>(&Bs[sr * ASTR2 + sh + 16]) = b2;
        *reinterpret_cast<bf16x8*>(&Bs[sr * ASTR2 + sh + 24]) = b3;
        __syncthreads();
#pragma unroll
        for (int kk = 0; kk < 2; ++kk) {
            bf16x8 af[4], bf[4];
#pragma unroll
            for (int mi = 0; mi < 4; ++mi)
                af[mi] = *reinterpret_cast<const bf16x8*>(
                    &As[(wr * 64 + mi * 16 + lo) * ASTR2 + kk * 32 + hi * 8]);
#pragma unroll
            for (int ni = 0; ni < 4; ++ni)
                bf[ni] = *reinterpret_cast<const bf16x8*>(
                    &Bs[(wc * 64 + ni * 16 + lo) * ASTR2 + kk * 32 + hi * 8]);
#pragma unroll
            for (int mi = 0; mi < 4; ++mi)
#pragma unroll
                for (int ni = 0; ni < 4; ++ni)
                    acc[mi][ni] = __builtin_amdgcn_mfma_f32_16x16x32_bf16(af[mi], bf[ni], acc[mi][ni], 0, 0, 0);
        }
    }

    f16* Sq = S + (size_t)q * HW * NSL;
#pragma unroll
    for (int mi = 0; mi < 4; ++mi) {
#pragma unroll
        for (int ni = 0; ni < 4; ++ni) {
            const int j = n0 + wc * 64 + ni * 16 + lo;
            if (j >= NSL) continue;
#pragma unroll
            for (int r = 0; r < 4; ++r) {
                const int m = m0 + wr * 64 + mi * 16 + hi * 4 + r;
                if (m < HW) Sq[(size_t)m * NSL + j] = (f16)acc[mi][ni][r];
            }
        }
    }
}

// ---------------------------------------------------------------------------
// K3: fused softmaxes (S is fp16).
//   Blocks [0, 1225): Ts row softmax, WAVE-PER-ROW (4 rows/block, no
//     barriers) + fused class row-sums R.
//   Blocks [1225, 1225+NQ*16): Tq column softmax.
// ---------------------------------------------------------------------------
#define TSBLK (NQ * HW / 4)   // 1225
__global__ __launch_bounds__(256) void k_soft(const f16* __restrict__ S,
                                              bf16* __restrict__ Ts,
                                              bf16* __restrict__ Tq,
                                              float* __restrict__ R) {
    const int bid = blockIdx.x;
    if (bid < TSBLK) {
        // ---- Ts role: one WAVE per (q,m) row; no __syncthreads ----
        const int lane = threadIdx.x & 63, w = threadIdx.x >> 6;
        const int qm = bid * 4 + w;          // < 4900
        const int q = qm / HW, m = qm - q * HW;
        const f16* row = S + (size_t)qm * NSL;
        bf16* orow = Ts + ((size_t)q * RPQ + m) * NSLP;
        float x[16];
        float mx = -1e30f;
#pragma unroll
        for (int p = 0; p < 16; ++p) {
            int j = lane + p * 64;
            x[p] = (j < NSL) ? (float)row[j] : -1e30f;
            mx = fmaxf(mx, x[p]);
        }
        for (int d = 32; d; d >>= 1) mx = fmaxf(mx, __shfl_xor(mx, d));
        float sum = 0.f;
#pragma unroll
        for (int p = 0; p < 16; ++p) {
            x[p] = expf(GAMMA * (x[p] - mx));   // pads -> exp(-inf) = 0
            sum += x[p];
        }
        for (int d = 32; d; d >>= 1) sum += __shfl_xor(sum, d);
        const float inv = 1.f / sum;
        float racc[NWAY];
#pragma unroll
        for (int s = 0; s < NWAY; ++s) racc[s] = 0.f;
#pragma unroll
        for (int p = 0; p < 16; ++p) {
            int j = lane + p * 64;
            if (j < NSL) {
                float val = x[p] * inv;
                orow[j] = (bf16)val;
                int cls = j / HW;
#pragma unroll
                for (int s = 0; s < NWAY; ++s) racc[s] += (cls == s) ? val : 0.f;
            } else if (j < NSLP) {
                orow[j] = (bf16)0.f;   // zero K-pad
            }
        }
#pragma unroll
        for (int s = 0; s < NWAY; ++s)
            for (int d = 32; d; d >>= 1) racc[s] += __shfl_xor(racc[s], d);
        if (lane == 0) {
#pragma unroll
            for (int s = 0; s < NWAY; ++s)
                R[((size_t)q * NWAY + s) * HW + m] = racc[s];
        }
    } else {
        // ---- Tq role: 64 columns per block, 4 m-groups of 49 ----
        const int idx2 = bid - TSBLK;
        const int q  = idx2 >> 4;
        const int bx = idx2 & 15;
        const int tx = threadIdx.x & 63;
        const int tg = threadIdx.x >> 6;
        const int j  = bx * 64 + tx;
        const int m0 = tg * 49;
        const f16* base = S + (size_t)q * HW * NSL;
        bf16* ob = Tq + (size_t)q * RPQ * NSLP;
        __shared__ float rmax[4][64], rsum[4][64];
        float xv[49];
        float mx = -1e30f;
        if (j < NSL) {
#pragma unroll
            for (int i = 0; i < 49; ++i) {
                xv[i] = (float)base[(m0 + i) * NSL + j];
                mx = fmaxf(mx, xv[i]);
            }
        }
        rmax[tg][tx] = mx;
        __syncthreads();
        mx = fmaxf(fmaxf(rmax[0][tx], rmax[1][tx]), fmaxf(rmax[2][tx], rmax[3][tx]));
        float sum = 0.f;
        if (j < NSL) {
#pragma unroll
            for (int i = 0; i < 49; ++i) {
                xv[i] = expf(GAMMA2 * (xv[i] - mx));
                sum += xv[i];
            }
        }
        rsum[tg][tx] = sum;
        __syncthreads();
        const float inv = 1.f / (rsum[0][tx] + rsum[1][tx] + rsum[2][tx] + rsum[3][tx]);
        if (j < NSL) {
#pragma unroll
            for (int i = 0; i < 49; ++i) ob[(size_t)(m0 + i) * NSLP + j] = (bf16)(xv[i] * inv);
        } else if (j < NSLP) {
#pragma unroll
            for (int i = 0; i < 49; ++i) ob[(size_t)(m0 + i) * NSLP + j] = (bf16)0.f;
        }
    }
}

// ---------------------------------------------------------------------------
// K4: M = 0.25 * Tq (196x992) * Ts^T (992x196) -> bf16, row stride MST=200.
// grid (4 j, 4 i, 25 q), 64 threads, one wave per 64x64 tile (400 blocks --
// the measured-good wide form).  Unroll 4: more loads in flight per wave
// (latency-bound kernel).  jt==0 blocks also compute rhs for free.
// ---------------------------------------------------------------------------
__global__ __launch_bounds__(64) void k_mgemm(const bf16* __restrict__ Tq,
                                              const bf16* __restrict__ Ts,
                                              bf16* __restrict__ Mb,
                                              float* __restrict__ rhs) {
    const int q  = blockIdx.z;
    const int it = blockIdx.y;
    const int jt = blockIdx.x;
    const int l  = threadIdx.x;
    const int lo = l & 15, hi = l >> 4;
    const bool dorhs = (jt == 0);
    const bf16* Ap[4];
    const bf16* Bp[4];
#pragma unroll
    for (int mi = 0; mi < 4; ++mi)
        Ap[mi] = Tq + ((size_t)q * RPQ + it * 64 + mi * 16 + lo) * NSLP + hi * 8;
#pragma unroll
    for (int ni = 0; ni < 4; ++ni)
        Bp[ni] = Ts + ((size_t)q * RPQ + jt * 64 + ni * 16 + lo) * NSLP + hi * 8;

    f32x4 acc[4][4] = {};
    float rsum[4] = {0.f, 0.f, 0.f, 0.f};
#pragma unroll 4
    for (int k0 = 0; k0 < NSLP; k0 += 32) {
        bf16x8 a[4], b[4];
#pragma unroll
        for (int mi = 0; mi < 4; ++mi) a[mi] = *reinterpret_cast<const bf16x8*>(Ap[mi] + k0);
#pragma unroll
        for (int ni = 0; ni < 4; ++ni) b[ni] = *reinterpret_cast<const bf16x8*>(Bp[ni] + k0);
        if (dorhs) {
#pragma unroll
            for (int mi = 0; mi < 4; ++mi)
#pragma unroll
                for (int e = 0; e < 8; ++e) rsum[mi] += (float)a[mi][e];
        }
#pragma unroll
        for (int mi = 0; mi < 4; ++mi)
#pragma unroll
            for (int ni = 0; ni < 4; ++ni)
                acc[mi][ni] = __builtin_amdgcn_mfma_f32_16x16x32_bf16(a[mi], b[ni], acc[mi][ni], 0, 0, 0);
    }

    if (dorhs) {
#pragma unroll
        for (int mi = 0; mi < 4; ++mi) {
            float v = rsum[mi];
            v += __shfl_xor(v, 16);
            v += __shfl_xor(v, 32);   // summed over the 4 hi-slices
            const int i = it * 64 + mi * 16 + lo;
            if (hi == 0 && i < HW) rhs[q * HW + i] = 1.f + 0.5f * v;
        }
    }

    bf16* Mq = Mb + (size_t)q * MRA * MST;
#pragma unroll
    for (int mi = 0; mi < 4; ++mi) {
#pragma unroll
        for (int ni = 0; ni < 4; ++ni) {
            const int j = jt * 64 + ni * 16 + lo;
            if (j >= MST) continue;
#pragma unroll
            for (int r = 0; r < 4; ++r) {
                const int i = it * 64 + mi * 16 + hi * 4 + r;
                if (i >= MRA) continue;
                Mq[(size_t)i * MST + j] =
                    (i < HW && j < HW) ? (bf16)(0.25f * acc[mi][ni][r]) : (bf16)0.f;
            }
        }
    }
}

// ---------------------------------------------------------------------------
// K5: per-query Katz solve, 1024 threads (16 waves), REGISTER-RESIDENT M.
// Each thread (r, qd) holds its 6-7 bf16x8 M-chunks in VGPRs (loaded once
// from L2-hot Mb); iterations are pure FMA + 2 barriers.  No LDS M staging
// (M is read NITER times total and L2-fits -- lesson #7), no bank aliasing.
//   - rhs read from global (precomputed by k_mgemm)
//   - NITER x (v <- rhs + M v): 4 col-quarters/row, LDS partial reduce
//   - out[q][s] = (R[s].v) / total
// M cols 196..199 are zeros (written by k_mgemm) -> full chunks are safe.
// ---------------------------------------------------------------------------
__global__ __launch_bounds__(1024) void k_solve2(const bf16* __restrict__ Mb,
                                                 const float* __restrict__ rhs,
                                                 const float* __restrict__ R,
                                                 float* __restrict__ out) {
    const int q = blockIdx.x;
    __shared__ __align__(16) float va[MST], vb[MST];
    __shared__ float part[4][256];
    __shared__ float rhsl[HW];
    __shared__ float cls[NWAY];
    const int t = threadIdx.x, lane = t & 63, w = t >> 6;

    // --- rhs from global ---
    if (t < MST) {
        float r = (t < HW) ? rhs[q * HW + t] : 0.f;
        if (t < HW) rhsl[t] = r;
        va[t] = r; vb[t] = 0.f;
    }

    // --- load this thread's M chunks into registers (one-time, L2-hot) ---
    const int r = t & 255, qd = t >> 8;
    const int cstart = (qd == 0) ? 0 : 7 + 6 * (qd - 1);   // {0,7,13,19}
    // chunk layout: qd0 -> mreg[0..6] = chunks 0..6; qd>0 -> mreg[0..5] =
    // chunks cstart..cstart+5 (mreg[6] unused, masked by the qd==0 branch).
    bf16x8 mreg[7];
    if (r < HW) {
        const bf16x8* mrow = reinterpret_cast<const bf16x8*>(Mb + (size_t)q * MRA * MST + (size_t)r * MST);
#pragma unroll
        for (int c = 0; c < 6; ++c) mreg[c] = mrow[cstart + c];
        if (qd == 0) mreg[6] = mrow[6];
    }
    __syncthreads();

    // --- iterations: pure register FMA + LDS partial reduce ---
    for (int it = 0; it < NITER; ++it) {
        const float* src = (it & 1) ? vb : va;
        float* dst = (it & 1) ? va : vb;
        float a = 0.f;
        if (r < HW) {
#pragma unroll
            for (int c = 0; c < 6; ++c) {
                const float* sp = &src[(cstart + c) * 8];
#pragma unroll
                for (int e = 0; e < 8; ++e) a += (float)mreg[c][e] * sp[e];
            }
            if (qd == 0) {
                const float* sp = &src[6 * 8];
#pragma unroll
                for (int e = 0; e < 8; ++e) a += (float)mreg[6][e] * sp[e];
            }
        }
        part[qd][r] = a;
        __syncthreads();
        if (qd == 0 && r < HW)
            dst[r] = rhsl[r] + (part[0][r] + part[1][r] + part[2][r] + part[3][r]);
        __syncthreads();
    }
    // NITER even -> final v in va

    if (w < NWAY) {
        const float* Rs = R + ((size_t)q * NWAY + w) * HW;
        float a = 0.f;
        for (int m = lane; m < HW; m += 64) a += va[m] * Rs[m];
        for (int d = 32; d; d >>= 1) a += __shfl_xor(a, d);
        if (lane == 0) cls[w] = a;
    }
    __syncthreads();
    if (t == 0) {
        float tot = cls[0] + cls[1] + cls[2] + cls[3] + cls[4];
        float invt = 1.f / tot;
        for (int s = 0; s < NWAY; ++s) out[q * NWAY + s] = cls[s] * invt;
    }
}

// ---------------------------------------------------------------------------
extern "C" void kernel_launch(void* const* d_in, const int* in_sizes, int n_in,
                              void* d_out, int out_size, void* d_ws, size_t ws_size,
                              hipStream_t stream) {
    const float* feat = (const float*)d_in[0];
    float* out = (float*)d_out;
    char* w = (char*)d_ws;

    // workspace layout (16B-aligned)
    f16*   S    = (f16*)w;    w += sizeof(f16)   * (size_t)NQ * HW * NSL;   //  9.61 MB
    bf16*  Ts   = (bf16*)w;   w += sizeof(bf16)  * (size_t)NQ * RPQ * NSLP; // 10.32 MB
    bf16*  Tq   = (bf16*)w;   w += sizeof(bf16)  * (size_t)NQ * RPQ * NSLP; // 10.32 MB
    bf16*  qnbt = (bf16*)w;   w += sizeof(bf16)  * (size_t)NQ * RPQ * CC;   //  6.66 MB
    bf16*  snbt = (bf16*)w;   w += sizeof(bf16)  * (size_t)BROWS * CC;      //  1.31 MB
    float* R    = (float*)w;  w += sizeof(float) * (size_t)NQ * NWAY * HW;
    float* rhs  = (float*)w;  w += sizeof(float) * (size_t)NQ * HW;
    // S is dead after both softmaxes -> bf16 M aliases it (2.08 MB <= 9.6 MB)
    bf16* Mb = (bf16*)S;

    k_norm  <<<dim3(13, NQ + NWAY), 256, 0, stream>>>(feat, qnbt, snbt);
    k_sgemm <<<dim3(8, 2, NQ), 256, 0, stream>>>(qnbt, snbt, S);
    k_soft  <<<TSBLK + NQ * 16, 256, 0, stream>>>(S, Ts, Tq, R);
    k_mgemm <<<dim3(4, 4, NQ), 64, 0, stream>>>(Tq, Ts, Mb, rhs);
    k_solve2<<<NQ, 1024, 0, stream>>>(Mb, rhs, R, out);
}